// Round 1
// baseline (2623.635 us; speedup 1.0000x reference)
//
#include <hip/hip_runtime.h>
#include <math.h>

#define BB 8
#define CC 320

// ---------------------------------------------------------------------------
// top-8 nearest-timestamp cross-sequence neighbors per row.
// Thread per row; insertion list kept in registers (all compile-time indices).
// Same-seq entries get +1e12 penalty: for T>=2 they are never picked (>=8
// cross candidates always exist); for T==1 (N=8) the self entry is picked 8th,
// exactly matching the reference's masked top-k behavior.
// ---------------------------------------------------------------------------
__global__ void topk8_kernel(const float* __restrict__ t, int N, int sh,
                             int* __restrict__ idx) {
    int n = blockIdx.x * 64 + threadIdx.x;
    if (n >= N) return;
    float tn = t[n];
    int seq = n >> sh;
    float d[8]; int id[8];
#pragma unroll
    for (int k = 0; k < 8; k++) { d[k] = 3.0e38f; id[k] = 0; }
    for (int m = 0; m < N; m++) {
        float v = fabsf(tn - t[m]);
        if ((m >> sh) == seq) v += 1.0e12f;
        if (v < d[7]) {
            int p = 0;
#pragma unroll
            for (int k = 0; k < 8; k++) p += (d[k] <= v) ? 1 : 0;
#pragma unroll
            for (int k = 7; k > 0; k--) {
                if (k > p) { d[k] = d[k - 1]; id[k] = id[k - 1]; }
            }
#pragma unroll
            for (int k = 0; k < 8; k++) {
                if (k == p) { d[k] = v; id[k] = m; }
            }
        }
    }
#pragma unroll
    for (int k = 0; k < 8; k++) idx[n * 8 + k] = id[k];
}

// ---------------------------------------------------------------------------
// Instance loss: one 64-lane wave per row. 17 dots of length 320 (pos + 8
// neg1 + 8 neg2), butterfly reduce, logsumexp - pos, atomic accumulate.
// ---------------------------------------------------------------------------
__global__ void inst_loss_kernel(const float* __restrict__ z1,
                                 const float* __restrict__ z2,
                                 const int* __restrict__ idx, int N,
                                 float* __restrict__ acc) {
    int wave = threadIdx.x >> 6;
    int lane = threadIdx.x & 63;
    int n = blockIdx.x * 4 + wave;
    if (n >= N) return;
    const float* z1n = z1 + (size_t)n * CC;
    const float* z2n = z2 + (size_t)n * CC;
    float a[5];
#pragma unroll
    for (int j = 0; j < 5; j++) a[j] = z1n[lane + 64 * j];
    float part[17];
    {
        float s = 0.f;
#pragma unroll
        for (int j = 0; j < 5; j++) s += a[j] * z2n[lane + 64 * j];
        part[0] = s;
    }
#pragma unroll
    for (int k = 0; k < 8; k++) {
        int p = idx[n * 8 + k];
        const float* r1 = z1 + (size_t)p * CC;
        const float* r2 = z2 + (size_t)p * CC;
        float s1 = 0.f, s2 = 0.f;
#pragma unroll
        for (int j = 0; j < 5; j++) {
            float av = a[j];
            s1 += av * r1[lane + 64 * j];
            s2 += av * r2[lane + 64 * j];
        }
        part[1 + k] = s1;
        part[9 + k] = s2;
    }
#pragma unroll
    for (int q = 0; q < 17; q++) {
        float v = part[q];
        for (int off = 32; off > 0; off >>= 1) v += __shfl_xor(v, off);
        part[q] = v;
    }
    if (lane == 0) {
        float m = part[0];
#pragma unroll
        for (int q = 1; q < 17; q++) m = fmaxf(m, part[q]);
        float s = 0.f;
#pragma unroll
        for (int q = 0; q < 17; q++) s += expf(part[q] - m);
        float lse = m + logf(s);
        atomicAdd(acc, lse - part[0]);
    }
}

// ---------------------------------------------------------------------------
// Fused temporal loss: per (batch, 64-row tile), loop over 64-col tiles of
// sim = Z Z^T (Z = concat(z1,z2) along T), 4x4 register tile per thread,
// LDS-staged K-chunks of 16, online softmax excluding the diagonal.
// Epilogue recomputes the cross term (cheap) and accumulates lse - cross.
// ---------------------------------------------------------------------------
__global__ void temporal_kernel(const float* __restrict__ z1,
                                const float* __restrict__ z2, int T,
                                float* __restrict__ acc) {
    int b = blockIdx.y;
    int n = 2 * T;
    int row0 = blockIdx.x * 64;
    int tx = threadIdx.x, ty = threadIdx.y;
    int tid = ty * 16 + tx;
    __shared__ __align__(16) float As[16][68];
    __shared__ __align__(16) float Bs[16][68];
    const float* zb1 = z1 + (size_t)b * T * CC;
    const float* zb2 = z2 + (size_t)b * T * CC;
    float M[4], S[4];
#pragma unroll
    for (int i = 0; i < 4; i++) { M[i] = -3.0e38f; S[i] = 0.f; }

    for (int jt = 0; jt < n; jt += 64) {
        float c[4][4];
#pragma unroll
        for (int i = 0; i < 4; i++)
#pragma unroll
            for (int j = 0; j < 4; j++) c[i][j] = 0.f;

        for (int kc = 0; kc < CC; kc += 16) {
#pragma unroll
            for (int q = 0; q < 4; q++) {
                int e = q * 256 + tid;
                int r = e >> 4, k = e & 15;
                int ra = row0 + r;
                float va = 0.f;
                if (ra < n) va = (ra < T) ? zb1[ra * CC + kc + k]
                                          : zb2[(ra - T) * CC + kc + k];
                As[k][r] = va;
                int rb = jt + r;
                float vb = 0.f;
                if (rb < n) vb = (rb < T) ? zb1[rb * CC + kc + k]
                                          : zb2[(rb - T) * CC + kc + k];
                Bs[k][r] = vb;
            }
            __syncthreads();
#pragma unroll
            for (int k = 0; k < 16; k++) {
                float4 a4 = *(const float4*)&As[k][ty * 4];
                float4 b4 = *(const float4*)&Bs[k][tx * 4];
                float av[4] = {a4.x, a4.y, a4.z, a4.w};
                float bv[4] = {b4.x, b4.y, b4.z, b4.w};
#pragma unroll
                for (int i = 0; i < 4; i++)
#pragma unroll
                    for (int j = 0; j < 4; j++) c[i][j] += av[i] * bv[j];
            }
            __syncthreads();
        }

        // online softmax update over this tile's 64 columns
#pragma unroll
        for (int i = 0; i < 4; i++) {
            int row = row0 + ty * 4 + i;
            if (row >= n) continue;
            float vv[4];
            float lm = -3.0e38f;
#pragma unroll
            for (int j = 0; j < 4; j++) {
                int col = jt + tx * 4 + j;
                float v = c[i][j];
                if (col >= n || col == row) v = -3.0e38f;
                vv[j] = v;
                lm = fmaxf(lm, v);
            }
#pragma unroll
            for (int off = 1; off < 16; off <<= 1)
                lm = fmaxf(lm, __shfl_xor(lm, off));
            float newM = fmaxf(M[i], lm);
            float ls = 0.f;
#pragma unroll
            for (int j = 0; j < 4; j++)
                ls += (vv[j] > -1.0e38f) ? expf(vv[j] - newM) : 0.f;
#pragma unroll
            for (int off = 1; off < 16; off <<= 1) ls += __shfl_xor(ls, off);
            S[i] = S[i] * expf(M[i] - newM) + ls;
            M[i] = newM;
        }
    }

    // epilogue: lse - cross per row
#pragma unroll
    for (int i = 0; i < 4; i++) {
        int row = row0 + ty * 4 + i;
        if (row >= n) continue;
        int partner = (row < T) ? row + T : row - T;
        const float* zr = (row < T) ? zb1 + row * CC : zb2 + (row - T) * CC;
        const float* zp =
            (partner < T) ? zb1 + partner * CC : zb2 + (partner - T) * CC;
        float cs = 0.f;
        for (int q = 0; q < CC / 16; q++)
            cs += zr[tx + 16 * q] * zp[tx + 16 * q];
#pragma unroll
        for (int off = 1; off < 16; off <<= 1) cs += __shfl_xor(cs, off);
        if (tx == 0) {
            float lse = M[i] + logf(S[i]);
            atomicAdd(acc, lse - cs);
        }
    }
}

// ---------------------------------------------------------------------------
// Pooling: max over time pairs for z1/z2, mean over pairs for t.
// ---------------------------------------------------------------------------
__global__ void pool_z_kernel(const float* __restrict__ z1i,
                              const float* __restrict__ z2i,
                              float* __restrict__ z1o,
                              float* __restrict__ z2o, int T2) {
    int i = blockIdx.x * blockDim.x + threadIdx.x;
    int total = BB * T2 * CC;
    if (i >= total) return;
    int c = i % CC;
    int t2 = (i / CC) % T2;
    int b = i / (CC * T2);
    size_t i0 = ((size_t)b * (2 * T2) + 2 * t2) * CC + c;
    z1o[i] = fmaxf(z1i[i0], z1i[i0 + CC]);
    z2o[i] = fmaxf(z2i[i0], z2i[i0 + CC]);
}

__global__ void pool_t_kernel(const float* __restrict__ ti,
                              float* __restrict__ to, int T2) {
    int i = blockIdx.x * blockDim.x + threadIdx.x;
    if (i >= BB * T2) return;
    int t2 = i % T2;
    int b = i / T2;
    to[i] = 0.5f * (ti[b * 2 * T2 + 2 * t2] + ti[b * 2 * T2 + 2 * t2 + 1]);
}

__global__ void finalize_kernel(const float* __restrict__ acc,
                                float* __restrict__ out) {
    float loss = 0.f;
    int Tl = 512;
    for (int l = 0; l < 10; l++) {
        loss += 0.5f * acc[l] / (float)(BB * Tl);
        if (l < 9) loss += 0.5f * acc[10 + l] / (float)(2 * BB * Tl);
        Tl >>= 1;
    }
    out[0] = loss / 10.f;
}

extern "C" void kernel_launch(void* const* d_in, const int* in_sizes, int n_in,
                              void* d_out, int out_size, void* d_ws,
                              size_t ws_size, hipStream_t stream) {
    const int Ts[10] = {512, 256, 128, 64, 32, 16, 8, 4, 2, 1};
    float* ws = (float*)d_ws;

    float* z1l[10]; float* z2l[10]; float* tl[10];
    z1l[0] = (float*)d_in[0];
    z2l[0] = (float*)d_in[1];
    tl[0] = (float*)d_in[2];
    size_t off = 0;
    for (int l = 1; l < 10; l++) { z1l[l] = ws + off; off += (size_t)BB * Ts[l] * CC; }
    for (int l = 1; l < 10; l++) { z2l[l] = ws + off; off += (size_t)BB * Ts[l] * CC; }
    for (int l = 1; l < 10; l++) { tl[l] = ws + off; off += (size_t)BB * Ts[l]; }
    int* idx = (int*)(ws + off); off += 4096 * 8;
    float* acc = ws + off; off += 32;

    hipMemsetAsync(acc, 0, 32 * sizeof(float), stream);

    for (int l = 0; l < 10; l++) {
        int T = Ts[l];
        int N = BB * T;
        int sh = 0;
        while ((1 << sh) < T) sh++;
        topk8_kernel<<<dim3((N + 63) / 64), dim3(64), 0, stream>>>(tl[l], N, sh, idx);
        inst_loss_kernel<<<dim3(N / 4), dim3(256), 0, stream>>>(z1l[l], z2l[l], idx, N, acc + l);
        if (T > 1) {
            int n = 2 * T;
            dim3 grid((n + 63) / 64, BB);
            temporal_kernel<<<grid, dim3(16, 16), 0, stream>>>(z1l[l], z2l[l], T, acc + 10 + l);
            int T2 = T / 2;
            int tot = BB * T2 * CC;
            pool_z_kernel<<<dim3((tot + 255) / 256), dim3(256), 0, stream>>>(z1l[l], z2l[l], z1l[l + 1], z2l[l + 1], T2);
            pool_t_kernel<<<dim3((BB * T2 + 63) / 64), dim3(64), 0, stream>>>(tl[l], tl[l + 1], T2);
        }
    }
    finalize_kernel<<<1, 1, 0, stream>>>(acc, (float*)d_out);
}

// Round 3
// 1140.702 us; speedup vs baseline: 2.3000x; 2.3000x over previous
//
#include <hip/hip_runtime.h>
#include <math.h>

#define BB 8
#define CC 320
#define ZTOT 1308160   // per-tensor pooled z elems, levels 1..9 (8*511*320)
#define TTOT 4088      // pooled t elems, levels 1..9 (8*511)
#define NROWS 8184     // instance rows across levels 0..9 (8*1023)
#define NROWS_T 16352  // temporal rows across levels 0..8 (16*1022)
#define NTBLK 2760     // temporal blocks across levels 0..8
#define PTOT 175072    // float2 partials total

// compile-time tables (constexpr -> folded, no scratch/loads)
constexpr int kT[10]       = {512,256,128,64,32,16,8,4,2,1};
constexpr int kLogT[10]    = {9,8,7,6,5,4,3,2,1,0};
constexpr int kZoff[10]    = {0,0,655360,983040,1146880,1228800,1269760,1290240,1300480,1305600};
constexpr int kToff[10]    = {0,0,2048,3072,3584,3840,3968,4032,4064,4080};
constexpr int kRowcum[11]  = {0,4096,6144,7168,7680,7936,8064,8128,8160,8176,8184};
constexpr int kTRowcum[10] = {0,8192,12288,14336,15360,15872,16128,16256,16320,16352};
constexpr int kTblkcum[10] = {0,2048,2560,2688,2720,2728,2736,2744,2752,2760};
constexpr int kNt[9]       = {16,8,4,2,1,1,1,1,1};
constexpr int kLogNt[9]    = {4,3,2,1,0,0,0,0,0};
constexpr int kPoff[9]     = {0,131072,163840,172032,174080,174592,174848,174976,175040};

// ---------------------------------------------------------------------------
// All pooled levels computed directly from level 0 (associative window max /
// window mean; T is even at every level so no truncation ever happens).
// ---------------------------------------------------------------------------
__global__ void pool_all(const float* __restrict__ z1,
                         const float* __restrict__ z2,
                         const float* __restrict__ t,
                         float* __restrict__ ws) {
    int gid = blockIdx.x * 256 + threadIdx.x;
    if (gid < 2 * ZTOT) {
        int which = gid >= ZTOT;
        int i = which ? gid - ZTOT : gid;
        int l = 1;
#pragma unroll
        for (int q = 2; q <= 9; q++) l = (i >= kZoff[q]) ? q : l;
        int rem = i - kZoff[l];
        int r = rem / CC;
        int c = rem - r * CC;
        int Tl = kT[l];
        int t2 = r & (Tl - 1);
        int b = r >> kLogT[l];
        int win = 512 / Tl;
        const float* src = which ? z2 : z1;
        const float* p = src + ((size_t)(b * 512 + t2 * win)) * CC + c;
        float v = p[0];
        for (int j = 1; j < win; j++) v = fmaxf(v, p[(size_t)j * CC]);
        ws[(which ? ZTOT : 0) + kZoff[l] + rem] = v;
    } else if (gid < 2 * ZTOT + TTOT) {
        int i = gid - 2 * ZTOT;
        int l = 1;
#pragma unroll
        for (int q = 2; q <= 9; q++) l = (i >= kToff[q]) ? q : l;
        int rem = i - kToff[l];
        int Tl = kT[l];
        int t2 = rem & (Tl - 1);
        int b = rem >> kLogT[l];
        int win = 512 / Tl;
        const float* p = t + b * 512 + t2 * win;
        float s = 0.f;
        for (int j = 0; j < win; j++) s += p[j];
        ws[2 * ZTOT + kToff[l] + rem] = s * (1.0f / win);
    }
}

// ---------------------------------------------------------------------------
// top-8 nearest-timestamp cross-sequence neighbors, all levels, thread/row.
// ---------------------------------------------------------------------------
__global__ void topk_all(const float* __restrict__ t0,
                         const float* __restrict__ ws, int* __restrict__ idx) {
    int gid = blockIdx.x * 256 + threadIdx.x;
    if (gid >= NROWS) return;
    int l = 0;
#pragma unroll
    for (int q = 1; q <= 9; q++) l = (gid >= kRowcum[q]) ? q : l;
    int n = gid - kRowcum[l];
    int N = 8 * kT[l];
    const float* tt = l ? ws + 2 * ZTOT + kToff[l] : t0;
    float tn = tt[n];
    int seq = n >> kLogT[l];
    float d[8]; int id[8];
#pragma unroll
    for (int k = 0; k < 8; k++) { d[k] = 3.0e38f; id[k] = 0; }
    for (int m = 0; m < N; m++) {
        float v = fabsf(tn - tt[m]);
        if ((m >> kLogT[l]) == seq) v += 1.0e12f;
        if (v < d[7]) {
            int p = 0;
#pragma unroll
            for (int k = 0; k < 8; k++) p += (d[k] <= v) ? 1 : 0;
#pragma unroll
            for (int k = 7; k > 0; k--)
                if (k > p) { d[k] = d[k - 1]; id[k] = id[k - 1]; }
#pragma unroll
            for (int k = 0; k < 8; k++)
                if (k == p) { d[k] = v; id[k] = m; }
        }
    }
#pragma unroll
    for (int k = 0; k < 8; k++) idx[gid * 8 + k] = id[k];
}

// ---------------------------------------------------------------------------
// Instance loss, all levels, one 64-lane wave per row.
// ---------------------------------------------------------------------------
__global__ void inst_all(const float* __restrict__ z1_0,
                         const float* __restrict__ z2_0,
                         const float* __restrict__ ws,
                         const int* __restrict__ idx,
                         float* __restrict__ acc) {
    int wave = threadIdx.x >> 6, lane = threadIdx.x & 63;
    int row = blockIdx.x * 4 + wave;
    if (row >= NROWS) return;
    int l = 0;
#pragma unroll
    for (int q = 1; q <= 9; q++) l = (row >= kRowcum[q]) ? q : l;
    int n = row - kRowcum[l];
    const float* z1 = l ? ws + kZoff[l] : z1_0;
    const float* z2 = l ? ws + ZTOT + kZoff[l] : z2_0;
    const float* z1n = z1 + (size_t)n * CC;
    const float* z2n = z2 + (size_t)n * CC;
    float a[5];
#pragma unroll
    for (int j = 0; j < 5; j++) a[j] = z1n[lane + 64 * j];
    float part[17];
    {
        float s = 0.f;
#pragma unroll
        for (int j = 0; j < 5; j++) s += a[j] * z2n[lane + 64 * j];
        part[0] = s;
    }
#pragma unroll
    for (int k = 0; k < 8; k++) {
        int p = idx[row * 8 + k];
        const float* r1 = z1 + (size_t)p * CC;
        const float* r2 = z2 + (size_t)p * CC;
        float s1 = 0.f, s2 = 0.f;
#pragma unroll
        for (int j = 0; j < 5; j++) {
            float av = a[j];
            s1 += av * r1[lane + 64 * j];
            s2 += av * r2[lane + 64 * j];
        }
        part[1 + k] = s1;
        part[9 + k] = s2;
    }
#pragma unroll
    for (int q = 0; q < 17; q++) {
        float v = part[q];
        for (int off = 32; off > 0; off >>= 1) v += __shfl_xor(v, off);
        part[q] = v;
    }
    if (lane == 0) {
        float m = part[0];
#pragma unroll
        for (int q = 1; q < 17; q++) m = fmaxf(m, part[q]);
        float s = 0.f;
#pragma unroll
        for (int q = 0; q < 17; q++) s += expf(part[q] - m);
        atomicAdd(acc + l, m + logf(s) - part[0]);
    }
}

// ---------------------------------------------------------------------------
// Temporal: one block per (level, batch, 64-row tile, 64-col tile). Computes
// the sim tile and writes per-row partial (max, sumexp) excluding diagonal.
// ---------------------------------------------------------------------------
__global__ void temporal_all(const float* __restrict__ z1_0,
                             const float* __restrict__ z2_0,
                             const float* __restrict__ ws,
                             float2* __restrict__ part) {
    int bid = blockIdx.x;
    int l = 0;
#pragma unroll
    for (int q = 1; q <= 8; q++) l = (bid >= kTblkcum[q]) ? q : l;
    int rem = bid - kTblkcum[l];
    int Tl = kT[l], n = 2 * Tl, nt = kNt[l], lnt = kLogNt[l];
    int ct = rem & (nt - 1);
    int rt = (rem >> lnt) & (nt - 1);
    int b = rem >> (2 * lnt);
    const float* zb1 = (l ? ws + kZoff[l] : z1_0) + (size_t)b * Tl * CC;
    const float* zb2 = (l ? ws + ZTOT + kZoff[l] : z2_0) + (size_t)b * Tl * CC;
    int row0 = rt * 64, jt = ct * 64;
    int tx = threadIdx.x & 15, ty = threadIdx.x >> 4;
    int tid = threadIdx.x;
    __shared__ __align__(16) float As[16][68];
    __shared__ __align__(16) float Bs[16][68];

    float c[4][4];
#pragma unroll
    for (int i = 0; i < 4; i++)
#pragma unroll
        for (int j = 0; j < 4; j++) c[i][j] = 0.f;

    for (int kc = 0; kc < CC; kc += 16) {
#pragma unroll
        for (int q = 0; q < 4; q++) {
            int e = q * 256 + tid;
            int r = e >> 4, k = e & 15;
            int ra = row0 + r;
            float va = 0.f;
            if (ra < n) va = (ra < Tl) ? zb1[ra * CC + kc + k]
                                       : zb2[(ra - Tl) * CC + kc + k];
            As[k][r] = va;
            int rb = jt + r;
            float vb = 0.f;
            if (rb < n) vb = (rb < Tl) ? zb1[rb * CC + kc + k]
                                       : zb2[(rb - Tl) * CC + kc + k];
            Bs[k][r] = vb;
        }
        __syncthreads();
#pragma unroll
        for (int k = 0; k < 16; k++) {
            float4 a4 = *(const float4*)&As[k][ty * 4];
            float4 b4 = *(const float4*)&Bs[k][tx * 4];
            float av[4] = {a4.x, a4.y, a4.z, a4.w};
            float bv[4] = {b4.x, b4.y, b4.z, b4.w};
#pragma unroll
            for (int i = 0; i < 4; i++)
#pragma unroll
                for (int j = 0; j < 4; j++) c[i][j] += av[i] * bv[j];
        }
        __syncthreads();
    }

#pragma unroll
    for (int i = 0; i < 4; i++) {
        int row = row0 + ty * 4 + i;
        float vv[4];
        float lm = -3.0e38f;
#pragma unroll
        for (int j = 0; j < 4; j++) {
            int col = jt + tx * 4 + j;
            float v = c[i][j];
            if (col >= n || col == row) v = -3.0e38f;
            vv[j] = v;
            lm = fmaxf(lm, v);
        }
#pragma unroll
        for (int off = 1; off < 16; off <<= 1)
            lm = fmaxf(lm, __shfl_xor(lm, off));
        float ls = 0.f;
#pragma unroll
        for (int j = 0; j < 4; j++)
            ls += (vv[j] > -1.0e38f) ? expf(vv[j] - lm) : 0.f;
#pragma unroll
        for (int off = 1; off < 16; off <<= 1) ls += __shfl_xor(ls, off);
        if (tx == 0 && row < n)
            part[kPoff[l] + ((b * n + row) << lnt) + ct] = make_float2(lm, ls);
    }
}

// ---------------------------------------------------------------------------
// Merge partials per row: logsumexp merge, subtract cross term, accumulate.
// ---------------------------------------------------------------------------
__global__ void merge_all(const float* __restrict__ z1_0,
                          const float* __restrict__ z2_0,
                          const float* __restrict__ ws,
                          const float2* __restrict__ part,
                          float* __restrict__ acc) {
    int wave = threadIdx.x >> 6, lane = threadIdx.x & 63;
    int row = blockIdx.x * 4 + wave;
    if (row >= NROWS_T) return;
    int l = 0;
#pragma unroll
    for (int q = 1; q <= 8; q++) l = (row >= kTRowcum[q]) ? q : l;
    int r = row - kTRowcum[l];
    int Tl = kT[l], n = 2 * Tl, nt = kNt[l], lnt = kLogNt[l];
    int b = r >> (kLogT[l] + 1);
    int rr = r & (n - 1);
    float m = -3.0e38f, s = 0.f;
    if (lane < nt) {
        float2 p = part[kPoff[l] + ((b * n + rr) << lnt) + lane];
        m = p.x; s = p.y;
    }
    float M = m;
#pragma unroll
    for (int off = 1; off < 64; off <<= 1) M = fmaxf(M, __shfl_xor(M, off));
    float e = (lane < nt) ? s * expf(m - M) : 0.f;
#pragma unroll
    for (int off = 1; off < 64; off <<= 1) e += __shfl_xor(e, off);
    int tloc = rr & (Tl - 1);
    const float* a = (l ? ws + kZoff[l] : z1_0) + (size_t)(b * Tl + tloc) * CC;
    const float* bb = (l ? ws + ZTOT + kZoff[l] : z2_0) + (size_t)(b * Tl + tloc) * CC;
    float cs = 0.f;
#pragma unroll
    for (int j = 0; j < 5; j++) cs += a[lane + 64 * j] * bb[lane + 64 * j];
#pragma unroll
    for (int off = 1; off < 64; off <<= 1) cs += __shfl_xor(cs, off);
    if (lane == 0) atomicAdd(acc + 10 + l, M + logf(e) - cs);
}

__global__ void finalize_kernel(const float* __restrict__ acc,
                                float* __restrict__ out) {
    float loss = 0.f;
    int Tl = 512;
    for (int l = 0; l < 10; l++) {
        loss += 0.5f * acc[l] / (float)(BB * Tl);
        if (l < 9) loss += 0.5f * acc[10 + l] / (float)(2 * BB * Tl);
        Tl >>= 1;
    }
    out[0] = loss / 10.f;
}

extern "C" void kernel_launch(void* const* d_in, const int* in_sizes, int n_in,
                              void* d_out, int out_size, void* d_ws,
                              size_t ws_size, hipStream_t stream) {
    const float* z1 = (const float*)d_in[0];
    const float* z2 = (const float*)d_in[1];
    const float* t  = (const float*)d_in[2];
    float* ws = (float*)d_ws;
    int* idx = (int*)(ws + 2 * ZTOT + TTOT);
    float2* part = (float2*)(ws + 2 * ZTOT + TTOT + NROWS * 8);
    float* acc = ws + 2 * ZTOT + TTOT + NROWS * 8 + 2 * PTOT;  // ~12.2 MB total

    hipMemsetAsync(acc, 0, 32 * sizeof(float), stream);
    pool_all<<<(2 * ZTOT + TTOT + 255) / 256, 256, 0, stream>>>(z1, z2, t, ws);
    topk_all<<<(NROWS + 255) / 256, 256, 0, stream>>>(t, ws, idx);
    inst_all<<<(NROWS + 3) / 4, 256, 0, stream>>>(z1, z2, ws, idx, acc);
    temporal_all<<<NTBLK, 256, 0, stream>>>(z1, z2, ws, part);
    merge_all<<<(NROWS_T + 3) / 4, 256, 0, stream>>>(z1, z2, ws, part, acc);
    finalize_kernel<<<1, 1, 0, stream>>>(acc, (float*)d_out);
}

// Round 4
// 608.888 us; speedup vs baseline: 4.3089x; 1.8734x over previous
//
#include <hip/hip_runtime.h>
#include <math.h>

#define BB 8
#define CC 320
#define ZTOT 1308160   // per-tensor pooled z elems, levels 1..9 (8*511*320)
#define TTOT 4088      // pooled t elems, levels 1..9 (8*511)
#define NROWS 8184     // instance rows across levels 0..9 (8*1023)
#define NROWS_T 16352  // temporal rows across levels 0..8 (16*1022)
#define NTBLK 2760     // temporal blocks across levels 0..8
#define PTOT 175072    // float2 partials total

// compile-time tables (constexpr -> folded, no scratch/loads)
constexpr int kT[10]       = {512,256,128,64,32,16,8,4,2,1};
constexpr int kLogT[10]    = {9,8,7,6,5,4,3,2,1,0};
constexpr int kZoff[10]    = {0,0,655360,983040,1146880,1228800,1269760,1290240,1300480,1305600};
constexpr int kToff[10]    = {0,0,2048,3072,3584,3840,3968,4032,4064,4080};
constexpr int kRowcum[11]  = {0,4096,6144,7168,7680,7936,8064,8128,8160,8176,8184};
constexpr int kTRowcum[10] = {0,8192,12288,14336,15360,15872,16128,16256,16320,16352};
constexpr int kTblkcum[10] = {0,2048,2560,2688,2720,2728,2736,2744,2752,2760};
constexpr int kNt[9]       = {16,8,4,2,1,1,1,1,1};
constexpr int kLogNt[9]    = {4,3,2,1,0,0,0,0,0};
constexpr int kPoff[9]     = {0,131072,163840,172032,174080,174592,174848,174976,175040};

// ---------------------------------------------------------------------------
// All pooled levels computed directly from level 0 (associative window max /
// window mean; T is even at every level so no truncation ever happens).
// ---------------------------------------------------------------------------
__global__ void pool_all(const float* __restrict__ z1,
                         const float* __restrict__ z2,
                         const float* __restrict__ t,
                         float* __restrict__ ws) {
    int gid = blockIdx.x * 256 + threadIdx.x;
    if (gid < 2 * ZTOT) {
        int which = gid >= ZTOT;
        int i = which ? gid - ZTOT : gid;
        int l = 1;
#pragma unroll
        for (int q = 2; q <= 9; q++) l = (i >= kZoff[q]) ? q : l;
        int rem = i - kZoff[l];
        int r = rem / CC;
        int c = rem - r * CC;
        int Tl = kT[l];
        int t2 = r & (Tl - 1);
        int b = r >> kLogT[l];
        int win = 512 / Tl;
        const float* src = which ? z2 : z1;
        const float* p = src + ((size_t)(b * 512 + t2 * win)) * CC + c;
        float v = p[0];
        for (int j = 1; j < win; j++) v = fmaxf(v, p[(size_t)j * CC]);
        ws[(which ? ZTOT : 0) + kZoff[l] + rem] = v;
    } else if (gid < 2 * ZTOT + TTOT) {
        int i = gid - 2 * ZTOT;
        int l = 1;
#pragma unroll
        for (int q = 2; q <= 9; q++) l = (i >= kToff[q]) ? q : l;
        int rem = i - kToff[l];
        int Tl = kT[l];
        int t2 = rem & (Tl - 1);
        int b = rem >> kLogT[l];
        int win = 512 / Tl;
        const float* p = t + b * 512 + t2 * win;
        float s = 0.f;
        for (int j = 0; j < win; j++) s += p[j];
        ws[2 * ZTOT + kToff[l] + rem] = s * (1.0f / win);
    }
}

// ---------------------------------------------------------------------------
// Fused top-8 + instance loss: one 64-lane wave per row.
// Lane L scans a contiguous candidate chunk keeping a sorted top-8; 6
// butterfly merge steps (bitonic lower-half + 12-CE cleanup, all
// compile-time indices, (d,id) lexicographic compare = reference
// tie-breaking). Then the 17-logit instance loss runs in the same wave.
// ---------------------------------------------------------------------------
#define PAIR_LT(da, ia, db, ib) ((da) < (db) || ((da) == (db) && (ia) < (ib)))
#define CE(x, y)                                                         \
    {                                                                    \
        if (PAIR_LT(nd[y], nid[y], nd[x], nid[x])) {                     \
            float td = nd[x]; nd[x] = nd[y]; nd[y] = td;                 \
            int ti = nid[x]; nid[x] = nid[y]; nid[y] = ti;               \
        }                                                                \
    }

__global__ void topk_inst_all(const float* __restrict__ z1_0,
                              const float* __restrict__ z2_0,
                              const float* __restrict__ t0,
                              const float* __restrict__ ws,
                              float* __restrict__ acc) {
    int wave = threadIdx.x >> 6, lane = threadIdx.x & 63;
    int row = blockIdx.x * 4 + wave;
    if (row >= NROWS) return;
    int l = 0;
#pragma unroll
    for (int q = 1; q <= 9; q++) l = (row >= kRowcum[q]) ? q : l;
    int n = row - kRowcum[l];
    int N = 8 * kT[l];
    const float* tt = l ? ws + 2 * ZTOT + kToff[l] : t0;
    float tn = tt[n];
    int seq = n >> kLogT[l];

    float d[8]; int id[8];
#pragma unroll
    for (int k = 0; k < 8; k++) { d[k] = 3.0e38f; id[k] = 0x7fffffff; }
    int chunk = (N + 63) >> 6;
    int mend = min(N, (lane + 1) * chunk);
    for (int m = lane * chunk; m < mend; m++) {
        float v = fabsf(tn - tt[m]);
        if ((m >> kLogT[l]) == seq) v += 1.0e12f;
        if (v < d[7]) {
            int p = 0;
#pragma unroll
            for (int k = 0; k < 8; k++) p += (d[k] <= v) ? 1 : 0;
#pragma unroll
            for (int k = 7; k > 0; k--)
                if (k > p) { d[k] = d[k - 1]; id[k] = id[k - 1]; }
#pragma unroll
            for (int k = 0; k < 8; k++)
                if (k == p) { d[k] = v; id[k] = m; }
        }
    }
    // butterfly merge: all lanes end with the global sorted top-8
#pragma unroll
    for (int s = 1; s <= 32; s <<= 1) {
        float pd[8]; int pid[8];
#pragma unroll
        for (int k = 0; k < 8; k++) {
            pd[k] = __shfl_xor(d[k], s);
            pid[k] = __shfl_xor(id[k], s);
        }
        float nd[8]; int nid[8];
#pragma unroll
        for (int i = 0; i < 8; i++) {
            bool tb = PAIR_LT(pd[7 - i], pid[7 - i], d[i], id[i]);
            nd[i] = tb ? pd[7 - i] : d[i];
            nid[i] = tb ? pid[7 - i] : id[i];
        }
        CE(0, 4) CE(1, 5) CE(2, 6) CE(3, 7)
        CE(0, 2) CE(1, 3) CE(4, 6) CE(5, 7)
        CE(0, 1) CE(2, 3) CE(4, 5) CE(6, 7)
#pragma unroll
        for (int k = 0; k < 8; k++) { d[k] = nd[k]; id[k] = nid[k]; }
    }

    // instance loss using id[0..7] (wave-uniform)
    const float* z1 = l ? ws + kZoff[l] : z1_0;
    const float* z2 = l ? ws + ZTOT + kZoff[l] : z2_0;
    const float* z1n = z1 + (size_t)n * CC;
    const float* z2n = z2 + (size_t)n * CC;
    float a[5];
#pragma unroll
    for (int j = 0; j < 5; j++) a[j] = z1n[lane + 64 * j];
    float part[17];
    {
        float s = 0.f;
#pragma unroll
        for (int j = 0; j < 5; j++) s += a[j] * z2n[lane + 64 * j];
        part[0] = s;
    }
#pragma unroll
    for (int k = 0; k < 8; k++) {
        int p = id[k];
        const float* r1 = z1 + (size_t)p * CC;
        const float* r2 = z2 + (size_t)p * CC;
        float s1 = 0.f, s2 = 0.f;
#pragma unroll
        for (int j = 0; j < 5; j++) {
            float av = a[j];
            s1 += av * r1[lane + 64 * j];
            s2 += av * r2[lane + 64 * j];
        }
        part[1 + k] = s1;
        part[9 + k] = s2;
    }
#pragma unroll
    for (int q = 0; q < 17; q++) {
        float v = part[q];
        for (int off = 32; off > 0; off >>= 1) v += __shfl_xor(v, off);
        part[q] = v;
    }
    if (lane == 0) {
        float m = part[0];
#pragma unroll
        for (int q = 1; q < 17; q++) m = fmaxf(m, part[q]);
        float s = 0.f;
#pragma unroll
        for (int q = 0; q < 17; q++) s += expf(part[q] - m);
        atomicAdd(acc + l, m + logf(s) - part[0]);
    }
}

// ---------------------------------------------------------------------------
// Temporal: one block per (level, batch, 64-row tile, 64-col tile). Computes
// the sim tile and writes per-row partial (max, sumexp) excluding diagonal.
// ---------------------------------------------------------------------------
__global__ void temporal_all(const float* __restrict__ z1_0,
                             const float* __restrict__ z2_0,
                             const float* __restrict__ ws,
                             float2* __restrict__ part) {
    int bid = blockIdx.x;
    int l = 0;
#pragma unroll
    for (int q = 1; q <= 8; q++) l = (bid >= kTblkcum[q]) ? q : l;
    int rem = bid - kTblkcum[l];
    int Tl = kT[l], n = 2 * Tl, nt = kNt[l], lnt = kLogNt[l];
    int ct = rem & (nt - 1);
    int rt = (rem >> lnt) & (nt - 1);
    int b = rem >> (2 * lnt);
    const float* zb1 = (l ? ws + kZoff[l] : z1_0) + (size_t)b * Tl * CC;
    const float* zb2 = (l ? ws + ZTOT + kZoff[l] : z2_0) + (size_t)b * Tl * CC;
    int row0 = rt * 64, jt = ct * 64;
    int tx = threadIdx.x & 15, ty = threadIdx.x >> 4;
    int tid = threadIdx.x;
    __shared__ __align__(16) float As[16][68];
    __shared__ __align__(16) float Bs[16][68];

    float c[4][4];
#pragma unroll
    for (int i = 0; i < 4; i++)
#pragma unroll
        for (int j = 0; j < 4; j++) c[i][j] = 0.f;

    for (int kc = 0; kc < CC; kc += 16) {
#pragma unroll
        for (int q = 0; q < 4; q++) {
            int e = q * 256 + tid;
            int r = e >> 4, k = e & 15;
            int ra = row0 + r;
            float va = 0.f;
            if (ra < n) va = (ra < Tl) ? zb1[ra * CC + kc + k]
                                       : zb2[(ra - Tl) * CC + kc + k];
            As[k][r] = va;
            int rb = jt + r;
            float vb = 0.f;
            if (rb < n) vb = (rb < Tl) ? zb1[rb * CC + kc + k]
                                       : zb2[(rb - Tl) * CC + kc + k];
            Bs[k][r] = vb;
        }
        __syncthreads();
#pragma unroll
        for (int k = 0; k < 16; k++) {
            float4 a4 = *(const float4*)&As[k][ty * 4];
            float4 b4 = *(const float4*)&Bs[k][tx * 4];
            float av[4] = {a4.x, a4.y, a4.z, a4.w};
            float bv[4] = {b4.x, b4.y, b4.z, b4.w};
#pragma unroll
            for (int i = 0; i < 4; i++)
#pragma unroll
                for (int j = 0; j < 4; j++) c[i][j] += av[i] * bv[j];
        }
        __syncthreads();
    }

#pragma unroll
    for (int i = 0; i < 4; i++) {
        int row = row0 + ty * 4 + i;
        float vv[4];
        float lm = -3.0e38f;
#pragma unroll
        for (int j = 0; j < 4; j++) {
            int col = jt + tx * 4 + j;
            float v = c[i][j];
            if (col >= n || col == row) v = -3.0e38f;
            vv[j] = v;
            lm = fmaxf(lm, v);
        }
#pragma unroll
        for (int off = 1; off < 16; off <<= 1)
            lm = fmaxf(lm, __shfl_xor(lm, off));
        float ls = 0.f;
#pragma unroll
        for (int j = 0; j < 4; j++)
            ls += (vv[j] > -1.0e38f) ? expf(vv[j] - lm) : 0.f;
#pragma unroll
        for (int off = 1; off < 16; off <<= 1) ls += __shfl_xor(ls, off);
        if (tx == 0 && row < n)
            part[kPoff[l] + ((b * n + row) << lnt) + ct] = make_float2(lm, ls);
    }
}

// ---------------------------------------------------------------------------
// Merge partials per row: logsumexp merge, subtract cross term, accumulate.
// ---------------------------------------------------------------------------
__global__ void merge_all(const float* __restrict__ z1_0,
                          const float* __restrict__ z2_0,
                          const float* __restrict__ ws,
                          const float2* __restrict__ part,
                          float* __restrict__ acc) {
    int wave = threadIdx.x >> 6, lane = threadIdx.x & 63;
    int row = blockIdx.x * 4 + wave;
    if (row >= NROWS_T) return;
    int l = 0;
#pragma unroll
    for (int q = 1; q <= 8; q++) l = (row >= kTRowcum[q]) ? q : l;
    int r = row - kTRowcum[l];
    int Tl = kT[l], n = 2 * Tl, nt = kNt[l], lnt = kLogNt[l];
    int b = r >> (kLogT[l] + 1);
    int rr = r & (n - 1);
    float m = -3.0e38f, s = 0.f;
    if (lane < nt) {
        float2 p = part[kPoff[l] + ((b * n + rr) << lnt) + lane];
        m = p.x; s = p.y;
    }
    float M = m;
#pragma unroll
    for (int off = 1; off < 64; off <<= 1) M = fmaxf(M, __shfl_xor(M, off));
    float e = (lane < nt) ? s * expf(m - M) : 0.f;
#pragma unroll
    for (int off = 1; off < 64; off <<= 1) e += __shfl_xor(e, off);
    int tloc = rr & (Tl - 1);
    const float* a = (l ? ws + kZoff[l] : z1_0) + (size_t)(b * Tl + tloc) * CC;
    const float* bb = (l ? ws + ZTOT + kZoff[l] : z2_0) + (size_t)(b * Tl + tloc) * CC;
    float cs = 0.f;
#pragma unroll
    for (int j = 0; j < 5; j++) cs += a[lane + 64 * j] * bb[lane + 64 * j];
#pragma unroll
    for (int off = 1; off < 64; off <<= 1) cs += __shfl_xor(cs, off);
    if (lane == 0) atomicAdd(acc + 10 + l, M + logf(e) - cs);
}

__global__ void finalize_kernel(const float* __restrict__ acc,
                                float* __restrict__ out) {
    float loss = 0.f;
    int Tl = 512;
    for (int l = 0; l < 10; l++) {
        loss += 0.5f * acc[l] / (float)(BB * Tl);
        if (l < 9) loss += 0.5f * acc[10 + l] / (float)(2 * BB * Tl);
        Tl >>= 1;
    }
    out[0] = loss / 10.f;
}

extern "C" void kernel_launch(void* const* d_in, const int* in_sizes, int n_in,
                              void* d_out, int out_size, void* d_ws,
                              size_t ws_size, hipStream_t stream) {
    const float* z1 = (const float*)d_in[0];
    const float* z2 = (const float*)d_in[1];
    const float* t  = (const float*)d_in[2];
    float* ws = (float*)d_ws;
    float2* part = (float2*)(ws + 2 * ZTOT + TTOT);
    float* acc = ws + 2 * ZTOT + TTOT + 2 * PTOT;  // ~12 MB total

    hipMemsetAsync(acc, 0, 32 * sizeof(float), stream);
    pool_all<<<(2 * ZTOT + TTOT + 255) / 256, 256, 0, stream>>>(z1, z2, t, ws);
    topk_inst_all<<<(NROWS + 3) / 4, 256, 0, stream>>>(z1, z2, t, ws, acc);
    temporal_all<<<NTBLK, 256, 0, stream>>>(z1, z2, ws, part);
    merge_all<<<(NROWS_T + 3) / 4, 256, 0, stream>>>(z1, z2, ws, part, acc);
    finalize_kernel<<<1, 1, 0, stream>>>(acc, (float*)d_out);
}

// Round 5
// 392.633 us; speedup vs baseline: 6.6822x; 1.5508x over previous
//
#include <hip/hip_runtime.h>
#include <math.h>

#define BB 8
#define CC 320
#define ZTOT 1308160   // per-tensor pooled z elems, levels 1..9 (8*511*320)
#define TTOT 4088      // pooled t elems, levels 1..9 (8*511)
#define NROWS 8184     // instance rows across levels 0..9 (8*1023)
#define NROWS_T 16352  // temporal rows across levels 0..8 (16*1022)
#define NTBLK 2760     // temporal blocks across levels 0..8
#define PTOT 175072    // float2 partials total
#define NSLOT 64       // accumulator slots per level (atomic spread)

// compile-time tables (constexpr -> folded, no scratch/loads)
constexpr int kT[10]       = {512,256,128,64,32,16,8,4,2,1};
constexpr int kLogT[10]    = {9,8,7,6,5,4,3,2,1,0};
constexpr int kZoff[10]    = {0,0,655360,983040,1146880,1228800,1269760,1290240,1300480,1305600};
constexpr int kToff[10]    = {0,0,2048,3072,3584,3840,3968,4032,4064,4080};
constexpr int kRowcum[11]  = {0,4096,6144,7168,7680,7936,8064,8128,8160,8176,8184};
constexpr int kTRowcum[10] = {0,8192,12288,14336,15360,15872,16128,16256,16320,16352};
constexpr int kTblkcum[10] = {0,2048,2560,2688,2720,2728,2736,2744,2752,2760};
constexpr int kNt[9]       = {16,8,4,2,1,1,1,1,1};
constexpr int kLogNt[9]    = {4,3,2,1,0,0,0,0,0};
constexpr int kPoff[9]     = {0,131072,163840,172032,174080,174592,174848,174976,175040};

// ---------------------------------------------------------------------------
// All pooled levels computed directly from level 0 (associative window max /
// window mean; T is even at every level so no truncation ever happens).
// ---------------------------------------------------------------------------
__global__ void pool_all(const float* __restrict__ z1,
                         const float* __restrict__ z2,
                         const float* __restrict__ t,
                         float* __restrict__ ws) {
    int gid = blockIdx.x * 256 + threadIdx.x;
    if (gid < 2 * ZTOT) {
        int which = gid >= ZTOT;
        int i = which ? gid - ZTOT : gid;
        int l = 1;
#pragma unroll
        for (int q = 2; q <= 9; q++) l = (i >= kZoff[q]) ? q : l;
        int rem = i - kZoff[l];
        int r = rem / CC;
        int c = rem - r * CC;
        int Tl = kT[l];
        int t2 = r & (Tl - 1);
        int b = r >> kLogT[l];
        int win = 512 / Tl;
        const float* src = which ? z2 : z1;
        const float* p = src + ((size_t)(b * 512 + t2 * win)) * CC + c;
        float v = p[0];
        for (int j = 1; j < win; j++) v = fmaxf(v, p[(size_t)j * CC]);
        ws[(which ? ZTOT : 0) + kZoff[l] + rem] = v;
    } else if (gid < 2 * ZTOT + TTOT) {
        int i = gid - 2 * ZTOT;
        int l = 1;
#pragma unroll
        for (int q = 2; q <= 9; q++) l = (i >= kToff[q]) ? q : l;
        int rem = i - kToff[l];
        int Tl = kT[l];
        int t2 = rem & (Tl - 1);
        int b = rem >> kLogT[l];
        int win = 512 / Tl;
        const float* p = t + b * 512 + t2 * win;
        float s = 0.f;
        for (int j = 0; j < win; j++) s += p[j];
        ws[2 * ZTOT + kToff[l] + rem] = s * (1.0f / win);
    }
}

// ---------------------------------------------------------------------------
// Fused top-8 + instance loss: one 64-lane wave per row.
// ---------------------------------------------------------------------------
#define PAIR_LT(da, ia, db, ib) ((da) < (db) || ((da) == (db) && (ia) < (ib)))
#define CE(x, y)                                                         \
    {                                                                    \
        if (PAIR_LT(nd[y], nid[y], nd[x], nid[x])) {                     \
            float td = nd[x]; nd[x] = nd[y]; nd[y] = td;                 \
            int ti = nid[x]; nid[x] = nid[y]; nid[y] = ti;               \
        }                                                                \
    }

__global__ void topk_inst_all(const float* __restrict__ z1_0,
                              const float* __restrict__ z2_0,
                              const float* __restrict__ t0,
                              const float* __restrict__ ws,
                              float* __restrict__ acc) {
    int wave = threadIdx.x >> 6, lane = threadIdx.x & 63;
    int row = blockIdx.x * 4 + wave;
    if (row >= NROWS) return;
    int l = 0;
#pragma unroll
    for (int q = 1; q <= 9; q++) l = (row >= kRowcum[q]) ? q : l;
    int n = row - kRowcum[l];
    int N = 8 * kT[l];
    const float* tt = l ? ws + 2 * ZTOT + kToff[l] : t0;
    float tn = tt[n];
    int seq = n >> kLogT[l];

    float d[8]; int id[8];
#pragma unroll
    for (int k = 0; k < 8; k++) { d[k] = 3.0e38f; id[k] = 0x7fffffff; }
    int chunk = (N + 63) >> 6;
    int mend = min(N, (lane + 1) * chunk);
    for (int m = lane * chunk; m < mend; m++) {
        float v = fabsf(tn - tt[m]);
        if ((m >> kLogT[l]) == seq) v += 1.0e12f;
        if (v < d[7]) {
            int p = 0;
#pragma unroll
            for (int k = 0; k < 8; k++) p += (d[k] <= v) ? 1 : 0;
#pragma unroll
            for (int k = 7; k > 0; k--)
                if (k > p) { d[k] = d[k - 1]; id[k] = id[k - 1]; }
#pragma unroll
            for (int k = 0; k < 8; k++)
                if (k == p) { d[k] = v; id[k] = m; }
        }
    }
    // butterfly merge: all lanes end with the global sorted top-8
#pragma unroll
    for (int s = 1; s <= 32; s <<= 1) {
        float pd[8]; int pid[8];
#pragma unroll
        for (int k = 0; k < 8; k++) {
            pd[k] = __shfl_xor(d[k], s);
            pid[k] = __shfl_xor(id[k], s);
        }
        float nd[8]; int nid[8];
#pragma unroll
        for (int i = 0; i < 8; i++) {
            bool tb = PAIR_LT(pd[7 - i], pid[7 - i], d[i], id[i]);
            nd[i] = tb ? pd[7 - i] : d[i];
            nid[i] = tb ? pid[7 - i] : id[i];
        }
        CE(0, 4) CE(1, 5) CE(2, 6) CE(3, 7)
        CE(0, 2) CE(1, 3) CE(4, 6) CE(5, 7)
        CE(0, 1) CE(2, 3) CE(4, 5) CE(6, 7)
#pragma unroll
        for (int k = 0; k < 8; k++) { d[k] = nd[k]; id[k] = nid[k]; }
    }

    // instance loss using id[0..7] (wave-uniform)
    const float* z1 = l ? ws + kZoff[l] : z1_0;
    const float* z2 = l ? ws + ZTOT + kZoff[l] : z2_0;
    const float* z1n = z1 + (size_t)n * CC;
    const float* z2n = z2 + (size_t)n * CC;
    float a[5];
#pragma unroll
    for (int j = 0; j < 5; j++) a[j] = z1n[lane + 64 * j];
    float part[17];
    {
        float s = 0.f;
#pragma unroll
        for (int j = 0; j < 5; j++) s += a[j] * z2n[lane + 64 * j];
        part[0] = s;
    }
#pragma unroll
    for (int k = 0; k < 8; k++) {
        int p = id[k];
        const float* r1 = z1 + (size_t)p * CC;
        const float* r2 = z2 + (size_t)p * CC;
        float s1 = 0.f, s2 = 0.f;
#pragma unroll
        for (int j = 0; j < 5; j++) {
            float av = a[j];
            s1 += av * r1[lane + 64 * j];
            s2 += av * r2[lane + 64 * j];
        }
        part[1 + k] = s1;
        part[9 + k] = s2;
    }
#pragma unroll
    for (int q = 0; q < 17; q++) {
        float v = part[q];
        for (int off = 32; off > 0; off >>= 1) v += __shfl_xor(v, off);
        part[q] = v;
    }
    if (lane == 0) {
        float m = part[0];
#pragma unroll
        for (int q = 1; q < 17; q++) m = fmaxf(m, part[q]);
        float s = 0.f;
#pragma unroll
        for (int q = 0; q < 17; q++) s += expf(part[q] - m);
        atomicAdd(acc + l * NSLOT + (row & (NSLOT - 1)),
                  m + logf(s) - part[0]);
    }
}

// ---------------------------------------------------------------------------
// Temporal: one block per (level, batch, 64-row tile, 64-col tile). Computes
// the sim tile and writes per-row partial (max, sumexp) excluding diagonal.
// ---------------------------------------------------------------------------
__global__ void temporal_all(const float* __restrict__ z1_0,
                             const float* __restrict__ z2_0,
                             const float* __restrict__ ws,
                             float2* __restrict__ part) {
    int bid = blockIdx.x;
    int l = 0;
#pragma unroll
    for (int q = 1; q <= 8; q++) l = (bid >= kTblkcum[q]) ? q : l;
    int rem = bid - kTblkcum[l];
    int Tl = kT[l], n = 2 * Tl, nt = kNt[l], lnt = kLogNt[l];
    int ct = rem & (nt - 1);
    int rt = (rem >> lnt) & (nt - 1);
    int b = rem >> (2 * lnt);
    const float* zb1 = (l ? ws + kZoff[l] : z1_0) + (size_t)b * Tl * CC;
    const float* zb2 = (l ? ws + ZTOT + kZoff[l] : z2_0) + (size_t)b * Tl * CC;
    int row0 = rt * 64, jt = ct * 64;
    int tx = threadIdx.x & 15, ty = threadIdx.x >> 4;
    int tid = threadIdx.x;
    __shared__ __align__(16) float As[16][68];
    __shared__ __align__(16) float Bs[16][68];

    float c[4][4];
#pragma unroll
    for (int i = 0; i < 4; i++)
#pragma unroll
        for (int j = 0; j < 4; j++) c[i][j] = 0.f;

    for (int kc = 0; kc < CC; kc += 16) {
#pragma unroll
        for (int q = 0; q < 4; q++) {
            int e = q * 256 + tid;
            int r = e >> 4, k = e & 15;
            int ra = row0 + r;
            float va = 0.f;
            if (ra < n) va = (ra < Tl) ? zb1[ra * CC + kc + k]
                                       : zb2[(ra - Tl) * CC + kc + k];
            As[k][r] = va;
            int rb = jt + r;
            float vb = 0.f;
            if (rb < n) vb = (rb < Tl) ? zb1[rb * CC + kc + k]
                                       : zb2[(rb - Tl) * CC + kc + k];
            Bs[k][r] = vb;
        }
        __syncthreads();
#pragma unroll
        for (int k = 0; k < 16; k++) {
            float4 a4 = *(const float4*)&As[k][ty * 4];
            float4 b4 = *(const float4*)&Bs[k][tx * 4];
            float av[4] = {a4.x, a4.y, a4.z, a4.w};
            float bv[4] = {b4.x, b4.y, b4.z, b4.w};
#pragma unroll
            for (int i = 0; i < 4; i++)
#pragma unroll
                for (int j = 0; j < 4; j++) c[i][j] += av[i] * bv[j];
        }
        __syncthreads();
    }

#pragma unroll
    for (int i = 0; i < 4; i++) {
        int row = row0 + ty * 4 + i;
        float vv[4];
        float lm = -3.0e38f;
#pragma unroll
        for (int j = 0; j < 4; j++) {
            int col = jt + tx * 4 + j;
            float v = c[i][j];
            if (col >= n || col == row) v = -3.0e38f;
            vv[j] = v;
            lm = fmaxf(lm, v);
        }
#pragma unroll
        for (int off = 1; off < 16; off <<= 1)
            lm = fmaxf(lm, __shfl_xor(lm, off));
        float ls = 0.f;
#pragma unroll
        for (int j = 0; j < 4; j++)
            ls += (vv[j] > -1.0e38f) ? expf(vv[j] - lm) : 0.f;
#pragma unroll
        for (int off = 1; off < 16; off <<= 1) ls += __shfl_xor(ls, off);
        if (tx == 0 && row < n)
            part[kPoff[l] + ((b * n + row) << lnt) + ct] = make_float2(lm, ls);
    }
}

// ---------------------------------------------------------------------------
// Merge partials per row: logsumexp merge, subtract cross term, accumulate
// into 64-way-spread slots (avoids same-address atomic serialization).
// ---------------------------------------------------------------------------
__global__ void merge_all(const float* __restrict__ z1_0,
                          const float* __restrict__ z2_0,
                          const float* __restrict__ ws,
                          const float2* __restrict__ part,
                          float* __restrict__ acc) {
    int wave = threadIdx.x >> 6, lane = threadIdx.x & 63;
    int row = blockIdx.x * 4 + wave;
    if (row >= NROWS_T) return;
    int l = 0;
#pragma unroll
    for (int q = 1; q <= 8; q++) l = (row >= kTRowcum[q]) ? q : l;
    int r = row - kTRowcum[l];
    int Tl = kT[l], n = 2 * Tl, nt = kNt[l], lnt = kLogNt[l];
    int b = r >> (kLogT[l] + 1);
    int rr = r & (n - 1);
    float m = -3.0e38f, s = 0.f;
    if (lane < nt) {
        float2 p = part[kPoff[l] + ((b * n + rr) << lnt) + lane];
        m = p.x; s = p.y;
    }
    float M = m;
#pragma unroll
    for (int off = 1; off < 64; off <<= 1) M = fmaxf(M, __shfl_xor(M, off));
    float e = (lane < nt) ? s * expf(m - M) : 0.f;
#pragma unroll
    for (int off = 1; off < 64; off <<= 1) e += __shfl_xor(e, off);
    int tloc = rr & (Tl - 1);
    const float* a = (l ? ws + kZoff[l] : z1_0) + (size_t)(b * Tl + tloc) * CC;
    const float* bb = (l ? ws + ZTOT + kZoff[l] : z2_0) + (size_t)(b * Tl + tloc) * CC;
    float cs = 0.f;
#pragma unroll
    for (int j = 0; j < 5; j++) cs += a[lane + 64 * j] * bb[lane + 64 * j];
#pragma unroll
    for (int off = 1; off < 64; off <<= 1) cs += __shfl_xor(cs, off);
    if (lane == 0)
        atomicAdd(acc + (10 + l) * NSLOT + (row & (NSLOT - 1)),
                  M + logf(e) - cs);
}

// ---------------------------------------------------------------------------
// Finalize: one 64-lane wave; lane j sums weighted slot j over all 19
// level-accumulators, butterfly reduce, lane 0 writes the scalar.
// ---------------------------------------------------------------------------
__global__ void finalize_kernel(const float* __restrict__ acc,
                                float* __restrict__ out) {
    int lane = threadIdx.x;
    float loss = 0.f;
#pragma unroll
    for (int l = 0; l < 10; l++)
        loss += 0.5f / (float)(BB * kT[l]) * acc[l * NSLOT + lane];
#pragma unroll
    for (int l = 0; l < 9; l++)
        loss += 0.5f / (float)(2 * BB * kT[l]) * acc[(10 + l) * NSLOT + lane];
#pragma unroll
    for (int off = 1; off < 64; off <<= 1) loss += __shfl_xor(loss, off);
    if (lane == 0) out[0] = loss / 10.f;
}

extern "C" void kernel_launch(void* const* d_in, const int* in_sizes, int n_in,
                              void* d_out, int out_size, void* d_ws,
                              size_t ws_size, hipStream_t stream) {
    const float* z1 = (const float*)d_in[0];
    const float* z2 = (const float*)d_in[1];
    const float* t  = (const float*)d_in[2];
    float* ws = (float*)d_ws;
    float2* part = (float2*)(ws + 2 * ZTOT + TTOT);
    float* acc = ws + 2 * ZTOT + TTOT + 2 * PTOT;  // 19*64 floats; ~12 MB total

    hipMemsetAsync(acc, 0, 19 * NSLOT * sizeof(float), stream);
    pool_all<<<(2 * ZTOT + TTOT + 255) / 256, 256, 0, stream>>>(z1, z2, t, ws);
    topk_inst_all<<<(NROWS + 3) / 4, 256, 0, stream>>>(z1, z2, t, ws, acc);
    temporal_all<<<NTBLK, 256, 0, stream>>>(z1, z2, ws, part);
    merge_all<<<(NROWS_T + 3) / 4, 256, 0, stream>>>(z1, z2, ws, part, acc);
    finalize_kernel<<<1, 64, 0, stream>>>(acc, (float*)d_out);
}

// Round 6
// 271.918 us; speedup vs baseline: 9.6486x; 1.4439x over previous
//
#include <hip/hip_runtime.h>
#include <math.h>

#define BB 8
#define CC 320
#define ZTOT 1308160   // per-tensor pooled z elems, levels 1..9 (8*511*320)
#define ZB 2618880     // per-tensor bf16 z elems, levels 0..9
#define TTOT 4088      // pooled t elems, levels 1..9 (8*511)
#define NROWS 8184     // instance rows across levels 0..9 (8*1023)
#define NROWS_T 16352  // temporal rows across levels 0..8 (16*1022)
#define NTBLK 720      // temporal 128x128 blocks across levels 0..8
#define PTOT 88032     // float2 partials total
#define NSLOT 64       // accumulator slots per level (atomic spread)

// float offsets inside ws
#define FT 2618880     // pooled t (zb occupies 2*ZB ushorts = 2618880 floats)
#define FPART 2622968  // partials (float2)
#define FACC 2799032   // accumulators

constexpr int kT[10]       = {512,256,128,64,32,16,8,4,2,1};
constexpr int kLogT[10]    = {9,8,7,6,5,4,3,2,1,0};
constexpr int kZoff[10]    = {0,0,655360,983040,1146880,1228800,1269760,1290240,1300480,1305600};
constexpr int kZBoff[10]   = {0,1310720,1966080,2293760,2457600,2539520,2580480,2600960,2611200,2616320};
constexpr int kToff[10]    = {0,0,2048,3072,3584,3840,3968,4032,4064,4080};
constexpr int kRowcum[11]  = {0,4096,6144,7168,7680,7936,8064,8128,8160,8176,8184};
constexpr int kTRowcum[10] = {0,8192,12288,14336,15360,15872,16128,16256,16320,16352};
constexpr int kTblk128[10] = {0,512,640,672,680,688,696,704,712,720};
constexpr int kNt128[9]    = {8,4,2,1,1,1,1,1,1};
constexpr int kLog128[9]   = {3,2,1,0,0,0,0,0,0};
constexpr int kPoff128[9]  = {0,65536,81920,86016,87040,87552,87808,87936,88000};

typedef short v8s __attribute__((ext_vector_type(8)));
typedef float v16f __attribute__((ext_vector_type(16)));

__device__ __forceinline__ unsigned short f2bf(float x) {
    unsigned int u = __float_as_uint(x);
    u = (u + 0x7FFFu + ((u >> 16) & 1u)) >> 16;
    return (unsigned short)u;
}
__device__ __forceinline__ float bfu(unsigned short u) {
    return __uint_as_float(((unsigned int)u) << 16);
}

// ---------------------------------------------------------------------------
// Pool all levels from level 0 (associative window max / mean); emit bf16 z
// for every level (incl. level-0 convert) and fp32 pooled t.
// ---------------------------------------------------------------------------
__global__ void pool_all(const float* __restrict__ z1,
                         const float* __restrict__ z2,
                         const float* __restrict__ t,
                         unsigned short* __restrict__ zb,
                         float* __restrict__ tpool) {
    int gid = blockIdx.x * 256 + threadIdx.x;
    if (gid < 2 * ZTOT) {
        int which = gid >= ZTOT;
        int i = which ? gid - ZTOT : gid;
        int l = 1;
#pragma unroll
        for (int q = 2; q <= 9; q++) l = (i >= kZoff[q]) ? q : l;
        int rem = i - kZoff[l];
        int r = rem / CC;
        int c = rem - r * CC;
        int Tl = kT[l];
        int t2 = r & (Tl - 1);
        int b = r >> kLogT[l];
        int win = 512 / Tl;
        const float* src = which ? z2 : z1;
        const float* p = src + ((size_t)(b * 512 + t2 * win)) * CC + c;
        float v = p[0];
        for (int j = 1; j < win; j++) v = fmaxf(v, p[(size_t)j * CC]);
        zb[(which ? ZB : 0) + kZBoff[l] + rem] = f2bf(v);
    } else if (gid < 2 * ZTOT + TTOT) {
        int i = gid - 2 * ZTOT;
        int l = 1;
#pragma unroll
        for (int q = 2; q <= 9; q++) l = (i >= kToff[q]) ? q : l;
        int rem = i - kToff[l];
        int Tl = kT[l];
        int t2 = rem & (Tl - 1);
        int b = rem >> kLogT[l];
        int win = 512 / Tl;
        const float* p = t + b * 512 + t2 * win;
        float s = 0.f;
        for (int j = 0; j < win; j++) s += p[j];
        tpool[kToff[l] + rem] = s * (1.0f / win);
    } else if (gid < 2 * ZTOT + TTOT + 2 * 1310720) {
        int i = gid - (2 * ZTOT + TTOT);
        if (i < 1310720) zb[i] = f2bf(z1[i]);
        else zb[ZB + (i - 1310720)] = f2bf(z2[i - 1310720]);
    }
}

// ---------------------------------------------------------------------------
// Fused top-8 + instance loss: one 64-lane wave per row (bf16 z reads).
// ---------------------------------------------------------------------------
#define PAIR_LT(da, ia, db, ib) ((da) < (db) || ((da) == (db) && (ia) < (ib)))
#define CE(x, y)                                                         \
    {                                                                    \
        if (PAIR_LT(nd[y], nid[y], nd[x], nid[x])) {                     \
            float td = nd[x]; nd[x] = nd[y]; nd[y] = td;                 \
            int ti = nid[x]; nid[x] = nid[y]; nid[y] = ti;               \
        }                                                                \
    }

__global__ void topk_inst_all(const unsigned short* __restrict__ zb,
                              const float* __restrict__ t0,
                              const float* __restrict__ tpool,
                              float* __restrict__ acc) {
    int wave = threadIdx.x >> 6, lane = threadIdx.x & 63;
    int row = blockIdx.x * 4 + wave;
    if (row >= NROWS) return;
    int l = 0;
#pragma unroll
    for (int q = 1; q <= 9; q++) l = (row >= kRowcum[q]) ? q : l;
    int n = row - kRowcum[l];
    int N = 8 * kT[l];
    const float* tt = l ? tpool + kToff[l] : t0;
    float tn = tt[n];
    int seq = n >> kLogT[l];

    float d[8]; int id[8];
#pragma unroll
    for (int k = 0; k < 8; k++) { d[k] = 3.0e38f; id[k] = 0x7fffffff; }
    int chunk = (N + 63) >> 6;
    int mend = min(N, (lane + 1) * chunk);
    for (int m = lane * chunk; m < mend; m++) {
        float v = fabsf(tn - tt[m]);
        if ((m >> kLogT[l]) == seq) v += 1.0e12f;
        if (v < d[7]) {
            int p = 0;
#pragma unroll
            for (int k = 0; k < 8; k++) p += (d[k] <= v) ? 1 : 0;
#pragma unroll
            for (int k = 7; k > 0; k--)
                if (k > p) { d[k] = d[k - 1]; id[k] = id[k - 1]; }
#pragma unroll
            for (int k = 0; k < 8; k++)
                if (k == p) { d[k] = v; id[k] = m; }
        }
    }
#pragma unroll
    for (int s = 1; s <= 32; s <<= 1) {
        float pd[8]; int pid[8];
#pragma unroll
        for (int k = 0; k < 8; k++) {
            pd[k] = __shfl_xor(d[k], s);
            pid[k] = __shfl_xor(id[k], s);
        }
        float nd[8]; int nid[8];
#pragma unroll
        for (int i = 0; i < 8; i++) {
            bool tb = PAIR_LT(pd[7 - i], pid[7 - i], d[i], id[i]);
            nd[i] = tb ? pd[7 - i] : d[i];
            nid[i] = tb ? pid[7 - i] : id[i];
        }
        CE(0, 4) CE(1, 5) CE(2, 6) CE(3, 7)
        CE(0, 2) CE(1, 3) CE(4, 6) CE(5, 7)
        CE(0, 1) CE(2, 3) CE(4, 5) CE(6, 7)
#pragma unroll
        for (int k = 0; k < 8; k++) { d[k] = nd[k]; id[k] = nid[k]; }
    }

    const unsigned short* z1 = zb + kZBoff[l];
    const unsigned short* z2 = zb + ZB + kZBoff[l];
    const unsigned short* z1n = z1 + (size_t)n * CC;
    const unsigned short* z2n = z2 + (size_t)n * CC;
    float a[5];
#pragma unroll
    for (int j = 0; j < 5; j++) a[j] = bfu(z1n[lane + 64 * j]);
    float part[17];
    {
        float s = 0.f;
#pragma unroll
        for (int j = 0; j < 5; j++) s += a[j] * bfu(z2n[lane + 64 * j]);
        part[0] = s;
    }
#pragma unroll
    for (int k = 0; k < 8; k++) {
        int p = id[k];
        const unsigned short* r1 = z1 + (size_t)p * CC;
        const unsigned short* r2 = z2 + (size_t)p * CC;
        float s1 = 0.f, s2 = 0.f;
#pragma unroll
        for (int j = 0; j < 5; j++) {
            float av = a[j];
            s1 += av * bfu(r1[lane + 64 * j]);
            s2 += av * bfu(r2[lane + 64 * j]);
        }
        part[1 + k] = s1;
        part[9 + k] = s2;
    }
#pragma unroll
    for (int q = 0; q < 17; q++) {
        float v = part[q];
        for (int off = 32; off > 0; off >>= 1) v += __shfl_xor(v, off);
        part[q] = v;
    }
    if (lane == 0) {
        float m = part[0];
#pragma unroll
        for (int q = 1; q < 17; q++) m = fmaxf(m, part[q]);
        float s = 0.f;
#pragma unroll
        for (int q = 0; q < 17; q++) s += expf(part[q] - m);
        atomicAdd(acc + l * NSLOT + (row & (NSLOT - 1)),
                  m + logf(s) - part[0]);
    }
}

// ---------------------------------------------------------------------------
// Temporal via bf16 MFMA: 128x128 block tile, 4 waves x (32 rows x 128 cols),
// mfma_f32_32x32x16_bf16, K staged 32 at a time in a lane-linear LDS layout.
// Per-row masked (max, sumexp) partial written per col-tile.
// ---------------------------------------------------------------------------
__global__ void __launch_bounds__(256) temporal_mfma(
        const unsigned short* __restrict__ zb, float2* __restrict__ part) {
    int bid = blockIdx.x;
    int l = 0;
#pragma unroll
    for (int q = 1; q <= 8; q++) l = (bid >= kTblk128[q]) ? q : l;
    int rem = bid - kTblk128[l];
    int Tl = kT[l], n = 2 * Tl, nt = kNt128[l], lnt = kLog128[l];
    int ct = rem & (nt - 1);
    int rt = (rem >> lnt) & (nt - 1);
    int b = rem >> (2 * lnt);
    const unsigned short* zb1 = zb + kZBoff[l] + (size_t)b * Tl * CC;
    const unsigned short* zb2 = zb + ZB + kZBoff[l] + (size_t)b * Tl * CC;
    int row0 = rt * 128, col0 = ct * 128;
    int tid = threadIdx.x;
    int w = tid >> 6, lane = tid & 63;
    __shared__ __align__(16) unsigned short As[4096];
    __shared__ __align__(16) unsigned short Bs[4096];

    v16f acc[4];
#pragma unroll
    for (int cs = 0; cs < 4; cs++)
#pragma unroll
        for (int e = 0; e < 16; e++) acc[cs][e] = 0.f;

    // per-thread staging constants (2 groups of (row, kbb))
    int sofq[2]; const unsigned short* srcA[2]; const unsigned short* srcB[2];
    bool vA[2], vB[2];
#pragma unroll
    for (int q = 0; q < 2; q++) {
        int g = q * 256 + tid;
        int r = g & 127, kbb = g >> 7;
        sofq[q] = (r >> 5) * 1024 + (kbb >> 1) * 512 + (kbb & 1) * 256 +
                  (r & 31) * 8;
        int ka = kbb * 8;
        int gr = row0 + r;
        vA[q] = gr < n;
        srcA[q] = vA[q] ? ((gr < Tl) ? zb1 + (size_t)gr * CC + ka
                                     : zb2 + (size_t)(gr - Tl) * CC + ka)
                        : zb1;
        int gc = col0 + r;
        vB[q] = gc < n;
        srcB[q] = vB[q] ? ((gc < Tl) ? zb1 + (size_t)gc * CC + ka
                                     : zb2 + (size_t)(gc - Tl) * CC + ka)
                        : zb1;
    }

    for (int kc = 0; kc < CC; kc += 32) {
#pragma unroll
        for (int q = 0; q < 2; q++) {
            uint4 av = vA[q] ? *(const uint4*)(srcA[q] + kc)
                             : make_uint4(0, 0, 0, 0);
            uint4 bv = vB[q] ? *(const uint4*)(srcB[q] + kc)
                             : make_uint4(0, 0, 0, 0);
            *(uint4*)(As + sofq[q]) = av;
            *(uint4*)(Bs + sofq[q]) = bv;
        }
        __syncthreads();
        const unsigned short* Ab = As + w * 1024;
#pragma unroll
        for (int cc = 0; cc < 2; cc++) {
            v8s af = *(const v8s*)(Ab + cc * 512 + lane * 8);
#pragma unroll
            for (int cs = 0; cs < 4; cs++) {
                v8s bf = *(const v8s*)(Bs + cs * 1024 + cc * 512 + lane * 8);
                acc[cs] = __builtin_amdgcn_mfma_f32_32x32x16_bf16(
                    af, bf, acc[cs], 0, 0, 0);
            }
        }
        __syncthreads();
    }

    // epilogue: masked per-row (max, sumexp) over this block's 128 cols
    int colin = lane & 31;
    int rowhalf = 4 * (lane >> 5);
#pragma unroll
    for (int r = 0; r < 16; r++) {
        int lrow = (r & 3) + 8 * (r >> 2) + rowhalf;
        int grow = row0 + w * 32 + lrow;
        float vals[4];
        float lm = -3.0e38f;
#pragma unroll
        for (int cs = 0; cs < 4; cs++) {
            int gcol = col0 + cs * 32 + colin;
            float v = acc[cs][r];
            if (gcol >= n || gcol == grow) v = -3.0e38f;
            vals[cs] = v;
            lm = fmaxf(lm, v);
        }
#pragma unroll
        for (int off = 1; off < 32; off <<= 1)
            lm = fmaxf(lm, __shfl_xor(lm, off));
        float ls = 0.f;
#pragma unroll
        for (int cs = 0; cs < 4; cs++)
            ls += (vals[cs] > -1.0e38f) ? expf(vals[cs] - lm) : 0.f;
#pragma unroll
        for (int off = 1; off < 32; off <<= 1) ls += __shfl_xor(ls, off);
        if (colin == 0 && grow < n)
            part[kPoff128[l] + ((b * n + grow) << lnt) + ct] =
                make_float2(lm, ls);
    }
}

// ---------------------------------------------------------------------------
// Merge partials per row: logsumexp merge, subtract cross term (bf16 inputs,
// fp32 accumulate), spread-slot atomic accumulate.
// ---------------------------------------------------------------------------
__global__ void merge_all(const unsigned short* __restrict__ zb,
                          const float2* __restrict__ part,
                          float* __restrict__ acc) {
    int wave = threadIdx.x >> 6, lane = threadIdx.x & 63;
    int row = blockIdx.x * 4 + wave;
    if (row >= NROWS_T) return;
    int l = 0;
#pragma unroll
    for (int q = 1; q <= 8; q++) l = (row >= kTRowcum[q]) ? q : l;
    int r = row - kTRowcum[l];
    int Tl = kT[l], n = 2 * Tl, nt = kNt128[l], lnt = kLog128[l];
    int b = r >> (kLogT[l] + 1);
    int rr = r & (n - 1);
    float m = -3.0e38f, s = 0.f;
    if (lane < nt) {
        float2 p = part[kPoff128[l] + ((b * n + rr) << lnt) + lane];
        m = p.x; s = p.y;
    }
    float M = m;
#pragma unroll
    for (int off = 1; off < 64; off <<= 1) M = fmaxf(M, __shfl_xor(M, off));
    float e = (lane < nt) ? s * expf(m - M) : 0.f;
#pragma unroll
    for (int off = 1; off < 64; off <<= 1) e += __shfl_xor(e, off);
    int tloc = rr & (Tl - 1);
    const unsigned short* za = zb + kZBoff[l] + (size_t)(b * Tl + tloc) * CC;
    const unsigned short* zc = zb + ZB + kZBoff[l] + (size_t)(b * Tl + tloc) * CC;
    float cs = 0.f;
#pragma unroll
    for (int j = 0; j < 5; j++)
        cs += bfu(za[lane + 64 * j]) * bfu(zc[lane + 64 * j]);
#pragma unroll
    for (int off = 1; off < 64; off <<= 1) cs += __shfl_xor(cs, off);
    if (lane == 0)
        atomicAdd(acc + (10 + l) * NSLOT + (row & (NSLOT - 1)),
                  M + logf(e) - cs);
}

__global__ void finalize_kernel(const float* __restrict__ acc,
                                float* __restrict__ out) {
    int lane = threadIdx.x;
    float loss = 0.f;
#pragma unroll
    for (int l = 0; l < 10; l++)
        loss += 0.5f / (float)(BB * kT[l]) * acc[l * NSLOT + lane];
#pragma unroll
    for (int l = 0; l < 9; l++)
        loss += 0.5f / (float)(2 * BB * kT[l]) * acc[(10 + l) * NSLOT + lane];
#pragma unroll
    for (int off = 1; off < 64; off <<= 1) loss += __shfl_xor(loss, off);
    if (lane == 0) out[0] = loss / 10.f;
}

extern "C" void kernel_launch(void* const* d_in, const int* in_sizes, int n_in,
                              void* d_out, int out_size, void* d_ws,
                              size_t ws_size, hipStream_t stream) {
    const float* z1 = (const float*)d_in[0];
    const float* z2 = (const float*)d_in[1];
    const float* t  = (const float*)d_in[2];
    float* ws = (float*)d_ws;
    unsigned short* zb = (unsigned short*)ws;
    float* tpool = ws + FT;
    float2* part = (float2*)(ws + FPART);
    float* acc = ws + FACC;  // 19*64 floats; total ws ~11.2 MB

    hipMemsetAsync(acc, 0, 19 * NSLOT * sizeof(float), stream);
    int ptot = 2 * ZTOT + TTOT + 2 * 1310720;
    pool_all<<<(ptot + 255) / 256, 256, 0, stream>>>(z1, z2, t, zb, tpool);
    topk_inst_all<<<(NROWS + 3) / 4, 256, 0, stream>>>(zb, t, tpool, acc);
    temporal_mfma<<<NTBLK, 256, 0, stream>>>(zb, part);
    merge_all<<<(NROWS_T + 3) / 4, 256, 0, stream>>>(zb, part, acc);
    finalize_kernel<<<1, 64, 0, stream>>>(acc, (float*)d_out);
}

// Round 7
// 221.516 us; speedup vs baseline: 11.8440x; 1.2275x over previous
//
#include <hip/hip_runtime.h>
#include <math.h>

#define BB 8
#define CC 320
#define ZB 2618880     // per-tensor bf16 z elems, levels 0..9
#define TTOT 4088      // pooled t elems, levels 1..9 (8*511)
#define NROWS 8184     // instance rows across levels 0..9 (8*1023)
#define NROWS_T 16352  // temporal rows across levels 0..8 (16*1022)
#define NTBLK 720      // temporal 128x128 blocks across levels 0..8
#define PTOT 88032     // float2 partials total
#define NSLOT 64       // accumulator slots per level (atomic spread)
#define NP1 327680     // stage-1 z threads: 2*8*64*320
#define NP2 40960      // stage-2 z threads: 2*8*8*320
#define NP3 5120       // stage-3 z threads: 2*8*320

// float offsets inside ws
#define FT 2618880     // pooled t (zb occupies 2*ZB ushorts = 2618880 floats)
#define FPART 2622968  // partials (float2)
#define FACC 2799032   // accumulators

constexpr int kT[10]       = {512,256,128,64,32,16,8,4,2,1};
constexpr int kLogT[10]    = {9,8,7,6,5,4,3,2,1,0};
constexpr int kZBoff[10]   = {0,1310720,1966080,2293760,2457600,2539520,2580480,2600960,2611200,2616320};
constexpr int kToff[10]    = {0,0,2048,3072,3584,3840,3968,4032,4064,4080};
constexpr int kRowcum[11]  = {0,4096,6144,7168,7680,7936,8064,8128,8160,8176,8184};
constexpr int kTRowcum[10] = {0,8192,12288,14336,15360,15872,16128,16256,16320,16352};
constexpr int kTblk128[10] = {0,512,640,672,680,688,696,704,712,720};
constexpr int kNt128[9]    = {8,4,2,1,1,1,1,1,1};
constexpr int kLog128[9]   = {3,2,1,0,0,0,0,0,0};
constexpr int kPoff128[9]  = {0,65536,81920,86016,87040,87552,87808,87936,88000};

typedef short v8s __attribute__((ext_vector_type(8)));
typedef float v16f __attribute__((ext_vector_type(16)));

__device__ __forceinline__ unsigned short f2bf(float x) {
    unsigned int u = __float_as_uint(x);
    u = (u + 0x7FFFu + ((u >> 16) & 1u)) >> 16;
    return (unsigned short)u;
}
__device__ __forceinline__ float bfu(unsigned short u) {
    return __uint_as_float(((unsigned int)u) << 16);
}

// ---------------------------------------------------------------------------
// Stage 1: fused level-0 bf16 convert + bf16 max-pool levels 1..3 (each z
// element read exactly once; all accesses coalesced across c) + fp32 t-pool.
// bf16 hierarchical max == round(fp32 max) since round-to-nearest is monotone.
// ---------------------------------------------------------------------------
__global__ void pool_lvl03(const float* __restrict__ z1,
                           const float* __restrict__ z2,
                           const float* __restrict__ t,
                           unsigned short* __restrict__ zb,
                           float* __restrict__ tpool) {
    int gid = blockIdx.x * 256 + threadIdx.x;
    if (gid < NP1) {
        int c = gid % CC;
        int rest = gid / CC;
        int ch = rest & 63;
        int b = (rest >> 6) & 7;
        int which = rest >> 9;
        const float* src =
            (which ? z2 : z1) + ((size_t)(b * 512 + ch * 8)) * CC + c;
        unsigned short* dst = zb + (size_t)which * ZB;
        float v[8];
#pragma unroll
        for (int j = 0; j < 8; j++) v[j] = src[(size_t)j * CC];
#pragma unroll
        for (int j = 0; j < 8; j++)
            dst[(size_t)(b * 512 + ch * 8 + j) * CC + c] = f2bf(v[j]);
        float m1[4];
#pragma unroll
        for (int j = 0; j < 4; j++) m1[j] = fmaxf(v[2 * j], v[2 * j + 1]);
#pragma unroll
        for (int j = 0; j < 4; j++)
            dst[kZBoff[1] + (size_t)(b * 256 + ch * 4 + j) * CC + c] =
                f2bf(m1[j]);
        float m2[2] = {fmaxf(m1[0], m1[1]), fmaxf(m1[2], m1[3])};
#pragma unroll
        for (int j = 0; j < 2; j++)
            dst[kZBoff[2] + (size_t)(b * 128 + ch * 2 + j) * CC + c] =
                f2bf(m2[j]);
        dst[kZBoff[3] + (size_t)(b * 64 + ch) * CC + c] =
            f2bf(fmaxf(m2[0], m2[1]));
    } else if (gid < NP1 + TTOT) {
        int i = gid - NP1;
        int l = 1;
#pragma unroll
        for (int q = 2; q <= 9; q++) l = (i >= kToff[q]) ? q : l;
        int rem = i - kToff[l];
        int Tl = kT[l];
        int t2 = rem & (Tl - 1);
        int b = rem >> kLogT[l];
        int win = 512 / Tl;
        const float* p = t + b * 512 + t2 * win;
        float s = 0.f;
        for (int j = 0; j < win; j++) s += p[j];
        tpool[kToff[l] + rem] = s * (1.0f / win);
    }
}

// ---------------------------------------------------------------------------
// Stage 2: bf16 max-pool levels 4..6 from level 3.
// ---------------------------------------------------------------------------
__global__ void pool_lvl46(unsigned short* __restrict__ zb) {
    int gid = blockIdx.x * 256 + threadIdx.x;
    if (gid >= NP2) return;
    int c = gid % CC;
    int rest = gid / CC;
    int ch = rest & 7;
    int b = (rest >> 3) & 7;
    int which = rest >> 6;
    unsigned short* base = zb + (size_t)which * ZB;
    const unsigned short* src =
        base + kZBoff[3] + (size_t)(b * 64 + ch * 8) * CC + c;
    float v[8];
#pragma unroll
    for (int j = 0; j < 8; j++) v[j] = bfu(src[(size_t)j * CC]);
    float m1[4];
#pragma unroll
    for (int j = 0; j < 4; j++) m1[j] = fmaxf(v[2 * j], v[2 * j + 1]);
#pragma unroll
    for (int j = 0; j < 4; j++)
        base[kZBoff[4] + (size_t)(b * 32 + ch * 4 + j) * CC + c] = f2bf(m1[j]);
    float m2[2] = {fmaxf(m1[0], m1[1]), fmaxf(m1[2], m1[3])};
#pragma unroll
    for (int j = 0; j < 2; j++)
        base[kZBoff[5] + (size_t)(b * 16 + ch * 2 + j) * CC + c] = f2bf(m2[j]);
    base[kZBoff[6] + (size_t)(b * 8 + ch) * CC + c] =
        f2bf(fmaxf(m2[0], m2[1]));
}

// ---------------------------------------------------------------------------
// Stage 3: bf16 max-pool levels 7..9 from level 6.
// ---------------------------------------------------------------------------
__global__ void pool_lvl79(unsigned short* __restrict__ zb) {
    int gid = blockIdx.x * 256 + threadIdx.x;
    if (gid >= NP3) return;
    int c = gid % CC;
    int rest = gid / CC;
    int b = rest & 7;
    int which = rest >> 3;
    unsigned short* base = zb + (size_t)which * ZB;
    const unsigned short* src = base + kZBoff[6] + (size_t)(b * 8) * CC + c;
    float v[8];
#pragma unroll
    for (int j = 0; j < 8; j++) v[j] = bfu(src[(size_t)j * CC]);
    float m1[4];
#pragma unroll
    for (int j = 0; j < 4; j++) m1[j] = fmaxf(v[2 * j], v[2 * j + 1]);
#pragma unroll
    for (int j = 0; j < 4; j++)
        base[kZBoff[7] + (size_t)(b * 4 + j) * CC + c] = f2bf(m1[j]);
    float m2[2] = {fmaxf(m1[0], m1[1]), fmaxf(m1[2], m1[3])};
#pragma unroll
    for (int j = 0; j < 2; j++)
        base[kZBoff[8] + (size_t)(b * 2 + j) * CC + c] = f2bf(m2[j]);
    base[kZBoff[9] + (size_t)b * CC + c] = f2bf(fmaxf(m2[0], m2[1]));
}

// ---------------------------------------------------------------------------
// Fused top-8 + instance loss: one 64-lane wave per row (bf16 z reads).
// ---------------------------------------------------------------------------
#define PAIR_LT(da, ia, db, ib) ((da) < (db) || ((da) == (db) && (ia) < (ib)))
#define CE(x, y)                                                         \
    {                                                                    \
        if (PAIR_LT(nd[y], nid[y], nd[x], nid[x])) {                     \
            float td = nd[x]; nd[x] = nd[y]; nd[y] = td;                 \
            int ti = nid[x]; nid[x] = nid[y]; nid[y] = ti;               \
        }                                                                \
    }

__global__ void topk_inst_all(const unsigned short* __restrict__ zb,
                              const float* __restrict__ t0,
                              const float* __restrict__ tpool,
                              float* __restrict__ acc) {
    int wave = threadIdx.x >> 6, lane = threadIdx.x & 63;
    int row = blockIdx.x * 4 + wave;
    if (row >= NROWS) return;
    int l = 0;
#pragma unroll
    for (int q = 1; q <= 9; q++) l = (row >= kRowcum[q]) ? q : l;
    int n = row - kRowcum[l];
    int N = 8 * kT[l];
    const float* tt = l ? tpool + kToff[l] : t0;
    float tn = tt[n];
    int seq = n >> kLogT[l];

    float d[8]; int id[8];
#pragma unroll
    for (int k = 0; k < 8; k++) { d[k] = 3.0e38f; id[k] = 0x7fffffff; }
    int chunk = (N + 63) >> 6;
    int mend = min(N, (lane + 1) * chunk);
    for (int m = lane * chunk; m < mend; m++) {
        float v = fabsf(tn - tt[m]);
        if ((m >> kLogT[l]) == seq) v += 1.0e12f;
        if (v < d[7]) {
            int p = 0;
#pragma unroll
            for (int k = 0; k < 8; k++) p += (d[k] <= v) ? 1 : 0;
#pragma unroll
            for (int k = 7; k > 0; k--)
                if (k > p) { d[k] = d[k - 1]; id[k] = id[k - 1]; }
#pragma unroll
            for (int k = 0; k < 8; k++)
                if (k == p) { d[k] = v; id[k] = m; }
        }
    }
#pragma unroll
    for (int s = 1; s <= 32; s <<= 1) {
        float pd[8]; int pid[8];
#pragma unroll
        for (int k = 0; k < 8; k++) {
            pd[k] = __shfl_xor(d[k], s);
            pid[k] = __shfl_xor(id[k], s);
        }
        float nd[8]; int nid[8];
#pragma unroll
        for (int i = 0; i < 8; i++) {
            bool tb = PAIR_LT(pd[7 - i], pid[7 - i], d[i], id[i]);
            nd[i] = tb ? pd[7 - i] : d[i];
            nid[i] = tb ? pid[7 - i] : id[i];
        }
        CE(0, 4) CE(1, 5) CE(2, 6) CE(3, 7)
        CE(0, 2) CE(1, 3) CE(4, 6) CE(5, 7)
        CE(0, 1) CE(2, 3) CE(4, 5) CE(6, 7)
#pragma unroll
        for (int k = 0; k < 8; k++) { d[k] = nd[k]; id[k] = nid[k]; }
    }

    const unsigned short* z1 = zb + kZBoff[l];
    const unsigned short* z2 = zb + ZB + kZBoff[l];
    const unsigned short* z1n = z1 + (size_t)n * CC;
    const unsigned short* z2n = z2 + (size_t)n * CC;
    float a[5];
#pragma unroll
    for (int j = 0; j < 5; j++) a[j] = bfu(z1n[lane + 64 * j]);
    float part[17];
    {
        float s = 0.f;
#pragma unroll
        for (int j = 0; j < 5; j++) s += a[j] * bfu(z2n[lane + 64 * j]);
        part[0] = s;
    }
#pragma unroll
    for (int k = 0; k < 8; k++) {
        int p = id[k];
        const unsigned short* r1 = z1 + (size_t)p * CC;
        const unsigned short* r2 = z2 + (size_t)p * CC;
        float s1 = 0.f, s2 = 0.f;
#pragma unroll
        for (int j = 0; j < 5; j++) {
            float av = a[j];
            s1 += av * bfu(r1[lane + 64 * j]);
            s2 += av * bfu(r2[lane + 64 * j]);
        }
        part[1 + k] = s1;
        part[9 + k] = s2;
    }
#pragma unroll
    for (int q = 0; q < 17; q++) {
        float v = part[q];
        for (int off = 32; off > 0; off >>= 1) v += __shfl_xor(v, off);
        part[q] = v;
    }
    if (lane == 0) {
        float m = part[0];
#pragma unroll
        for (int q = 1; q < 17; q++) m = fmaxf(m, part[q]);
        float s = 0.f;
#pragma unroll
        for (int q = 0; q < 17; q++) s += expf(part[q] - m);
        atomicAdd(acc + l * NSLOT + (row & (NSLOT - 1)),
                  m + logf(s) - part[0]);
    }
}

// ---------------------------------------------------------------------------
// Temporal via bf16 MFMA: 128x128 block tile, 4 waves x (32 rows x 128 cols),
// mfma_f32_32x32x16_bf16, K staged 32 at a time in a lane-linear LDS layout.
// Per-row masked (max, sumexp) partial written per col-tile.
// ---------------------------------------------------------------------------
__global__ void __launch_bounds__(256) temporal_mfma(
        const unsigned short* __restrict__ zb, float2* __restrict__ part) {
    int bid = blockIdx.x;
    int l = 0;
#pragma unroll
    for (int q = 1; q <= 8; q++) l = (bid >= kTblk128[q]) ? q : l;
    int rem = bid - kTblk128[l];
    int Tl = kT[l], n = 2 * Tl, nt = kNt128[l], lnt = kLog128[l];
    int ct = rem & (nt - 1);
    int rt = (rem >> lnt) & (nt - 1);
    int b = rem >> (2 * lnt);
    const unsigned short* zb1 = zb + kZBoff[l] + (size_t)b * Tl * CC;
    const unsigned short* zb2 = zb + ZB + kZBoff[l] + (size_t)b * Tl * CC;
    int row0 = rt * 128, col0 = ct * 128;
    int tid = threadIdx.x;
    int w = tid >> 6, lane = tid & 63;
    __shared__ __align__(16) unsigned short As[4096];
    __shared__ __align__(16) unsigned short Bs[4096];

    v16f acc[4];
#pragma unroll
    for (int cs = 0; cs < 4; cs++)
#pragma unroll
        for (int e = 0; e < 16; e++) acc[cs][e] = 0.f;

    int sofq[2]; const unsigned short* srcA[2]; const unsigned short* srcB[2];
    bool vA[2], vB[2];
#pragma unroll
    for (int q = 0; q < 2; q++) {
        int g = q * 256 + tid;
        int r = g & 127, kbb = g >> 7;
        sofq[q] = (r >> 5) * 1024 + (kbb >> 1) * 512 + (kbb & 1) * 256 +
                  (r & 31) * 8;
        int ka = kbb * 8;
        int gr = row0 + r;
        vA[q] = gr < n;
        srcA[q] = vA[q] ? ((gr < Tl) ? zb1 + (size_t)gr * CC + ka
                                     : zb2 + (size_t)(gr - Tl) * CC + ka)
                        : zb1;
        int gc = col0 + r;
        vB[q] = gc < n;
        srcB[q] = vB[q] ? ((gc < Tl) ? zb1 + (size_t)gc * CC + ka
                                     : zb2 + (size_t)(gc - Tl) * CC + ka)
                        : zb1;
    }

    for (int kc = 0; kc < CC; kc += 32) {
#pragma unroll
        for (int q = 0; q < 2; q++) {
            uint4 av = vA[q] ? *(const uint4*)(srcA[q] + kc)
                             : make_uint4(0, 0, 0, 0);
            uint4 bv = vB[q] ? *(const uint4*)(srcB[q] + kc)
                             : make_uint4(0, 0, 0, 0);
            *(uint4*)(As + sofq[q]) = av;
            *(uint4*)(Bs + sofq[q]) = bv;
        }
        __syncthreads();
        const unsigned short* Ab = As + w * 1024;
#pragma unroll
        for (int cc = 0; cc < 2; cc++) {
            v8s af = *(const v8s*)(Ab + cc * 512 + lane * 8);
#pragma unroll
            for (int cs = 0; cs < 4; cs++) {
                v8s bf = *(const v8s*)(Bs + cs * 1024 + cc * 512 + lane * 8);
                acc[cs] = __builtin_amdgcn_mfma_f32_32x32x16_bf16(
                    af, bf, acc[cs], 0, 0, 0);
            }
        }
        __syncthreads();
    }

    int colin = lane & 31;
    int rowhalf = 4 * (lane >> 5);
#pragma unroll
    for (int r = 0; r < 16; r++) {
        int lrow = (r & 3) + 8 * (r >> 2) + rowhalf;
        int grow = row0 + w * 32 + lrow;
        float vals[4];
        float lm = -3.0e38f;
#pragma unroll
        for (int cs = 0; cs < 4; cs++) {
            int gcol = col0 + cs * 32 + colin;
            float v = acc[cs][r];
            if (gcol >= n || gcol == grow) v = -3.0e38f;
            vals[cs] = v;
            lm = fmaxf(lm, v);
        }
#pragma unroll
        for (int off = 1; off < 32; off <<= 1)
            lm = fmaxf(lm, __shfl_xor(lm, off));
        float ls = 0.f;
#pragma unroll
        for (int cs = 0; cs < 4; cs++)
            ls += (vals[cs] > -1.0e38f) ? expf(vals[cs] - lm) : 0.f;
#pragma unroll
        for (int off = 1; off < 32; off <<= 1) ls += __shfl_xor(ls, off);
        if (colin == 0 && grow < n)
            part[kPoff128[l] + ((b * n + grow) << lnt) + ct] =
                make_float2(lm, ls);
    }
}

// ---------------------------------------------------------------------------
// Merge partials per row: logsumexp merge, subtract cross term (bf16 inputs,
// fp32 accumulate), spread-slot atomic accumulate.
// ---------------------------------------------------------------------------
__global__ void merge_all(const unsigned short* __restrict__ zb,
                          const float2* __restrict__ part,
                          float* __restrict__ acc) {
    int wave = threadIdx.x >> 6, lane = threadIdx.x & 63;
    int row = blockIdx.x * 4 + wave;
    if (row >= NROWS_T) return;
    int l = 0;
#pragma unroll
    for (int q = 1; q <= 8; q++) l = (row >= kTRowcum[q]) ? q : l;
    int r = row - kTRowcum[l];
    int Tl = kT[l], n = 2 * Tl, nt = kNt128[l], lnt = kLog128[l];
    int b = r >> (kLogT[l] + 1);
    int rr = r & (n - 1);
    float m = -3.0e38f, s = 0.f;
    if (lane < nt) {
        float2 p = part[kPoff128[l] + ((b * n + rr) << lnt) + lane];
        m = p.x; s = p.y;
    }
    float M = m;
#pragma unroll
    for (int off = 1; off < 64; off <<= 1) M = fmaxf(M, __shfl_xor(M, off));
    float e = (lane < nt) ? s * expf(m - M) : 0.f;
#pragma unroll
    for (int off = 1; off < 64; off <<= 1) e += __shfl_xor(e, off);
    int tloc = rr & (Tl - 1);
    const unsigned short* za = zb + kZBoff[l] + (size_t)(b * Tl + tloc) * CC;
    const unsigned short* zc = zb + ZB + kZBoff[l] + (size_t)(b * Tl + tloc) * CC;
    float cs = 0.f;
#pragma unroll
    for (int j = 0; j < 5; j++)
        cs += bfu(za[lane + 64 * j]) * bfu(zc[lane + 64 * j]);
#pragma unroll
    for (int off = 1; off < 64; off <<= 1) cs += __shfl_xor(cs, off);
    if (lane == 0)
        atomicAdd(acc + (10 + l) * NSLOT + (row & (NSLOT - 1)),
                  M + logf(e) - cs);
}

__global__ void finalize_kernel(const float* __restrict__ acc,
                                float* __restrict__ out) {
    int lane = threadIdx.x;
    float loss = 0.f;
#pragma unroll
    for (int l = 0; l < 10; l++)
        loss += 0.5f / (float)(BB * kT[l]) * acc[l * NSLOT + lane];
#pragma unroll
    for (int l = 0; l < 9; l++)
        loss += 0.5f / (float)(2 * BB * kT[l]) * acc[(10 + l) * NSLOT + lane];
#pragma unroll
    for (int off = 1; off < 64; off <<= 1) loss += __shfl_xor(loss, off);
    if (lane == 0) out[0] = loss / 10.f;
}

extern "C" void kernel_launch(void* const* d_in, const int* in_sizes, int n_in,
                              void* d_out, int out_size, void* d_ws,
                              size_t ws_size, hipStream_t stream) {
    const float* z1 = (const float*)d_in[0];
    const float* z2 = (const float*)d_in[1];
    const float* t  = (const float*)d_in[2];
    float* ws = (float*)d_ws;
    unsigned short* zb = (unsigned short*)ws;
    float* tpool = ws + FT;
    float2* part = (float2*)(ws + FPART);
    float* acc = ws + FACC;  // 19*64 floats; total ws ~11.2 MB

    hipMemsetAsync(acc, 0, 19 * NSLOT * sizeof(float), stream);
    pool_lvl03<<<(NP1 + TTOT + 255) / 256, 256, 0, stream>>>(z1, z2, t, zb, tpool);
    pool_lvl46<<<(NP2 + 255) / 256, 256, 0, stream>>>(zb);
    pool_lvl79<<<(NP3 + 255) / 256, 256, 0, stream>>>(zb);
    topk_inst_all<<<(NROWS + 3) / 4, 256, 0, stream>>>(zb, t, tpool, acc);
    temporal_mfma<<<NTBLK, 256, 0, stream>>>(zb, part);
    merge_all<<<(NROWS_T + 3) / 4, 256, 0, stream>>>(zb, part, acc);
    finalize_kernel<<<1, 64, 0, stream>>>(acc, (float*)d_out);
}

// Round 8
// 191.039 us; speedup vs baseline: 13.7335x; 1.1595x over previous
//
#include <hip/hip_runtime.h>
#include <math.h>

#define BB 8
#define CC 320
#define ZB 2618880     // per-tensor bf16 z elems, levels 0..9
#define TTOT 4088      // pooled t elems, levels 1..9 (8*511)
#define NROWS 8184     // instance rows across levels 0..9 (8*1023)
#define NROWS_T 16352  // temporal rows across levels 0..8 (16*1022)
#define NTBLK 720      // temporal 128x128 blocks across levels 0..8
#define PTOT 88032     // float2 partials total
#define NSLOT 64       // accumulator slots per level (atomic spread)
#define NP1 327680     // stage-1 z threads: 2*8*64*320
#define NP2 5120       // stage-2 z threads: 2*8*320

// float offsets inside ws
#define FT 2618880     // pooled t (zb occupies 2*ZB ushorts = 2618880 floats)
#define FPART 2622968  // partials (float2)
#define FACC 2799032   // accumulators

constexpr int kT[10]       = {512,256,128,64,32,16,8,4,2,1};
constexpr int kLogT[10]    = {9,8,7,6,5,4,3,2,1,0};
constexpr int kZBoff[10]   = {0,1310720,1966080,2293760,2457600,2539520,2580480,2600960,2611200,2616320};
constexpr int kToff[10]    = {0,0,2048,3072,3584,3840,3968,4032,4064,4080};
constexpr int kRowcum[11]  = {0,4096,6144,7168,7680,7936,8064,8128,8160,8176,8184};
constexpr int kTRowcum[10] = {0,8192,12288,14336,15360,15872,16128,16256,16320,16352};
constexpr int kTblk128[10] = {0,512,640,672,680,688,696,704,712,720};
constexpr int kNt128[9]    = {8,4,2,1,1,1,1,1,1};
constexpr int kLog128[9]   = {3,2,1,0,0,0,0,0,0};
constexpr int kPoff128[9]  = {0,65536,81920,86016,87040,87552,87808,87936,88000};

typedef short v8s __attribute__((ext_vector_type(8)));
typedef float v16f __attribute__((ext_vector_type(16)));

__device__ __forceinline__ unsigned short f2bf(float x) {
    unsigned int u = __float_as_uint(x);
    u = (u + 0x7FFFu + ((u >> 16) & 1u)) >> 16;
    return (unsigned short)u;
}
__device__ __forceinline__ float bfu(unsigned short u) {
    return __uint_as_float(((unsigned int)u) << 16);
}

// ---------------------------------------------------------------------------
// Stage 1: fused level-0 bf16 convert + bf16 max-pool levels 1..3 + fp32
// t-pool (all levels) + acc zero-init (fold: saves a memset dispatch; all
// atomics happen in later stream-ordered dispatches).
// ---------------------------------------------------------------------------
__global__ void pool_lvl03(const float* __restrict__ z1,
                           const float* __restrict__ z2,
                           const float* __restrict__ t,
                           unsigned short* __restrict__ zb,
                           float* __restrict__ tpool,
                           float* __restrict__ acc) {
    int gid = blockIdx.x * 256 + threadIdx.x;
    if (gid < 19 * NSLOT) acc[gid] = 0.f;
    if (gid < NP1) {
        int c = gid % CC;
        int rest = gid / CC;
        int ch = rest & 63;
        int b = (rest >> 6) & 7;
        int which = rest >> 9;
        const float* src =
            (which ? z2 : z1) + ((size_t)(b * 512 + ch * 8)) * CC + c;
        unsigned short* dst = zb + (size_t)which * ZB;
        float v[8];
#pragma unroll
        for (int j = 0; j < 8; j++) v[j] = src[(size_t)j * CC];
#pragma unroll
        for (int j = 0; j < 8; j++)
            dst[(size_t)(b * 512 + ch * 8 + j) * CC + c] = f2bf(v[j]);
        float m1[4];
#pragma unroll
        for (int j = 0; j < 4; j++) m1[j] = fmaxf(v[2 * j], v[2 * j + 1]);
#pragma unroll
        for (int j = 0; j < 4; j++)
            dst[kZBoff[1] + (size_t)(b * 256 + ch * 4 + j) * CC + c] =
                f2bf(m1[j]);
        float m2[2] = {fmaxf(m1[0], m1[1]), fmaxf(m1[2], m1[3])};
#pragma unroll
        for (int j = 0; j < 2; j++)
            dst[kZBoff[2] + (size_t)(b * 128 + ch * 2 + j) * CC + c] =
                f2bf(m2[j]);
        dst[kZBoff[3] + (size_t)(b * 64 + ch) * CC + c] =
            f2bf(fmaxf(m2[0], m2[1]));
    } else if (gid < NP1 + TTOT) {
        int i = gid - NP1;
        int l = 1;
#pragma unroll
        for (int q = 2; q <= 9; q++) l = (i >= kToff[q]) ? q : l;
        int rem = i - kToff[l];
        int Tl = kT[l];
        int t2 = rem & (Tl - 1);
        int b = rem >> kLogT[l];
        int win = 512 / Tl;
        const float* p = t + b * 512 + t2 * win;
        float s = 0.f;
        for (int j = 0; j < win; j++) s += p[j];
        tpool[kToff[l] + rem] = s * (1.0f / win);
    }
}

// ---------------------------------------------------------------------------
// Stage 2: bf16 max-pool levels 4..9 from level 3 (one thread per (which,b,c),
// 64-deep column; bf16 max of bf16 values is exact, so this is bit-identical
// to per-level rounding).
// ---------------------------------------------------------------------------
__global__ void pool_lvl49(unsigned short* __restrict__ zb) {
    int gid = blockIdx.x * 256 + threadIdx.x;
    if (gid >= NP2) return;
    int c = gid % CC;
    int r2 = gid / CC;
    int b = r2 & 7;
    int which = r2 >> 3;
    unsigned short* base = zb + (size_t)which * ZB;
    const unsigned short* src = base + kZBoff[3] + (size_t)(b * 64) * CC + c;
    float a[32];
#pragma unroll
    for (int j = 0; j < 32; j++)
        a[j] = fmaxf(bfu(src[(size_t)(2 * j) * CC]),
                     bfu(src[(size_t)(2 * j + 1) * CC]));
#pragma unroll
    for (int j = 0; j < 32; j++)
        base[kZBoff[4] + (size_t)(b * 32 + j) * CC + c] = f2bf(a[j]);
#pragma unroll
    for (int j = 0; j < 16; j++) a[j] = fmaxf(a[2 * j], a[2 * j + 1]);
#pragma unroll
    for (int j = 0; j < 16; j++)
        base[kZBoff[5] + (size_t)(b * 16 + j) * CC + c] = f2bf(a[j]);
#pragma unroll
    for (int j = 0; j < 8; j++) a[j] = fmaxf(a[2 * j], a[2 * j + 1]);
#pragma unroll
    for (int j = 0; j < 8; j++)
        base[kZBoff[6] + (size_t)(b * 8 + j) * CC + c] = f2bf(a[j]);
#pragma unroll
    for (int j = 0; j < 4; j++) a[j] = fmaxf(a[2 * j], a[2 * j + 1]);
#pragma unroll
    for (int j = 0; j < 4; j++)
        base[kZBoff[7] + (size_t)(b * 4 + j) * CC + c] = f2bf(a[j]);
#pragma unroll
    for (int j = 0; j < 2; j++) a[j] = fmaxf(a[2 * j], a[2 * j + 1]);
#pragma unroll
    for (int j = 0; j < 2; j++)
        base[kZBoff[8] + (size_t)(b * 2 + j) * CC + c] = f2bf(a[j]);
    base[kZBoff[9] + (size_t)b * CC + c] = f2bf(fmaxf(a[0], a[1]));
}

// ---------------------------------------------------------------------------
// Fused top-8 + instance loss, one 64-lane wave per row.
// Phase A (lanes 0-7): t is SORTED per sequence, so lane s binary-searches
// sequence s and runs two-pointer expansion; 8 extraction rounds of packed
// (dist,idx) u64 shfl-min across the 8 lanes give the exact reference top-8
// set (u64 tie-break == top_k stability; fp dists bit-identical to |a-b|).
// Self-row candidate (1e12, n) is only ever picked at T==1, matching the
// reference's same-seq masking. Phase B (all 64 lanes): 17 dots + lse.
// ---------------------------------------------------------------------------
__global__ void topk_inst_all(const unsigned short* __restrict__ zb,
                              const float* __restrict__ t0,
                              const float* __restrict__ tpool,
                              float* __restrict__ acc) {
    int wave = threadIdx.x >> 6, lane = threadIdx.x & 63;
    int row = blockIdx.x * 4 + wave;
    if (row >= NROWS) return;
    int l = 0;
#pragma unroll
    for (int q = 1; q <= 9; q++) l = (row >= kRowcum[q]) ? q : l;
    int n = row - kRowcum[l];
    int T = kT[l];
    const float* tt = l ? tpool + kToff[l] : t0;
    int seq = n >> kLogT[l];
    float tn = tt[n];

    int idx8[8];
    if (lane < 8) {
        const float* ts = tt + lane * T;
        bool own = (lane == seq);
        int lo = 0, hi = T;
        while (lo < hi) {
            int mid = (lo + hi) >> 1;
            if (ts[mid] < tn) lo = mid + 1; else hi = mid;
        }
        int il = lo - 1, ih = lo;
        float dl = (il >= 0) ? (tn - ts[il]) : 3.0e38f;
        float dh = (ih < T) ? (ts[ih] - tn) : 3.0e38f;
#pragma unroll
        for (int r = 0; r < 8; r++) {
            bool pickLo = (dl <= dh);
            float dmin = own ? 1.0e12f : (pickLo ? dl : dh);
            int midx = own ? n : (lane * T + (pickLo ? il : ih));
            unsigned long long key =
                ((unsigned long long)__float_as_uint(dmin) << 32) |
                (unsigned int)midx;
            unsigned long long o;
            o = __shfl_xor(key, 1); key = (key < o) ? key : o;
            o = __shfl_xor(key, 2); key = (key < o) ? key : o;
            o = __shfl_xor(key, 4); key = (key < o) ? key : o;
            int widx = (int)(unsigned int)(key & 0xffffffffull);
            idx8[r] = widx;
            if (!own && widx == midx) {
                if (pickLo) { il--; dl = (il >= 0) ? (tn - ts[il]) : 3.0e38f; }
                else        { ih++; dh = (ih < T)  ? (ts[ih] - tn) : 3.0e38f; }
            }
        }
    }

    // Phase B: instance loss (idx broadcast from lane 0)
    const unsigned short* z1 = zb + kZBoff[l];
    const unsigned short* z2 = zb + ZB + kZBoff[l];
    const unsigned short* z1n = z1 + (size_t)n * CC;
    const unsigned short* z2n = z2 + (size_t)n * CC;
    float a[5];
#pragma unroll
    for (int j = 0; j < 5; j++) a[j] = bfu(z1n[lane + 64 * j]);
    float part[17];
    {
        float s = 0.f;
#pragma unroll
        for (int j = 0; j < 5; j++) s += a[j] * bfu(z2n[lane + 64 * j]);
        part[0] = s;
    }
#pragma unroll
    for (int k = 0; k < 8; k++) {
        int p = __shfl(idx8[k], 0);
        const unsigned short* r1 = z1 + (size_t)p * CC;
        const unsigned short* r2 = z2 + (size_t)p * CC;
        float s1 = 0.f, s2 = 0.f;
#pragma unroll
        for (int j = 0; j < 5; j++) {
            float av = a[j];
            s1 += av * bfu(r1[lane + 64 * j]);
            s2 += av * bfu(r2[lane + 64 * j]);
        }
        part[1 + k] = s1;
        part[9 + k] = s2;
    }
#pragma unroll
    for (int q = 0; q < 17; q++) {
        float v = part[q];
        for (int off = 32; off > 0; off >>= 1) v += __shfl_xor(v, off);
        part[q] = v;
    }
    if (lane == 0) {
        float m = part[0];
#pragma unroll
        for (int q = 1; q < 17; q++) m = fmaxf(m, part[q]);
        float s = 0.f;
#pragma unroll
        for (int q = 0; q < 17; q++) s += expf(part[q] - m);
        atomicAdd(acc + l * NSLOT + (row & (NSLOT - 1)),
                  m + logf(s) - part[0]);
    }
}

// ---------------------------------------------------------------------------
// Temporal via bf16 MFMA: 128x128 block tile, 4 waves x (32 rows x 128 cols),
// mfma_f32_32x32x16_bf16, K staged 32 at a time in a lane-linear LDS layout.
// Per-row masked (max, sumexp) partial written per col-tile.
// ---------------------------------------------------------------------------
__global__ void __launch_bounds__(256) temporal_mfma(
        const unsigned short* __restrict__ zb, float2* __restrict__ part) {
    int bid = blockIdx.x;
    int l = 0;
#pragma unroll
    for (int q = 1; q <= 8; q++) l = (bid >= kTblk128[q]) ? q : l;
    int rem = bid - kTblk128[l];
    int Tl = kT[l], n = 2 * Tl, nt = kNt128[l], lnt = kLog128[l];
    int ct = rem & (nt - 1);
    int rt = (rem >> lnt) & (nt - 1);
    int b = rem >> (2 * lnt);
    const unsigned short* zb1 = zb + kZBoff[l] + (size_t)b * Tl * CC;
    const unsigned short* zb2 = zb + ZB + kZBoff[l] + (size_t)b * Tl * CC;
    int row0 = rt * 128, col0 = ct * 128;
    int tid = threadIdx.x;
    int w = tid >> 6, lane = tid & 63;
    __shared__ __align__(16) unsigned short As[4096];
    __shared__ __align__(16) unsigned short Bs[4096];

    v16f acc[4];
#pragma unroll
    for (int cs = 0; cs < 4; cs++)
#pragma unroll
        for (int e = 0; e < 16; e++) acc[cs][e] = 0.f;

    int sofq[2]; const unsigned short* srcA[2]; const unsigned short* srcB[2];
    bool vA[2], vB[2];
#pragma unroll
    for (int q = 0; q < 2; q++) {
        int g = q * 256 + tid;
        int r = g & 127, kbb = g >> 7;
        sofq[q] = (r >> 5) * 1024 + (kbb >> 1) * 512 + (kbb & 1) * 256 +
                  (r & 31) * 8;
        int ka = kbb * 8;
        int gr = row0 + r;
        vA[q] = gr < n;
        srcA[q] = vA[q] ? ((gr < Tl) ? zb1 + (size_t)gr * CC + ka
                                     : zb2 + (size_t)(gr - Tl) * CC + ka)
                        : zb1;
        int gc = col0 + r;
        vB[q] = gc < n;
        srcB[q] = vB[q] ? ((gc < Tl) ? zb1 + (size_t)gc * CC + ka
                                     : zb2 + (size_t)(gc - Tl) * CC + ka)
                        : zb1;
    }

    for (int kc = 0; kc < CC; kc += 32) {
#pragma unroll
        for (int q = 0; q < 2; q++) {
            uint4 av = vA[q] ? *(const uint4*)(srcA[q] + kc)
                             : make_uint4(0, 0, 0, 0);
            uint4 bv = vB[q] ? *(const uint4*)(srcB[q] + kc)
                             : make_uint4(0, 0, 0, 0);
            *(uint4*)(As + sofq[q]) = av;
            *(uint4*)(Bs + sofq[q]) = bv;
        }
        __syncthreads();
        const unsigned short* Ab = As + w * 1024;
#pragma unroll
        for (int cc = 0; cc < 2; cc++) {
            v8s af = *(const v8s*)(Ab + cc * 512 + lane * 8);
#pragma unroll
            for (int cs = 0; cs < 4; cs++) {
                v8s bf = *(const v8s*)(Bs + cs * 1024 + cc * 512 + lane * 8);
                acc[cs] = __builtin_amdgcn_mfma_f32_32x32x16_bf16(
                    af, bf, acc[cs], 0, 0, 0);
            }
        }
        __syncthreads();
    }

    int colin = lane & 31;
    int rowhalf = 4 * (lane >> 5);
#pragma unroll
    for (int r = 0; r < 16; r++) {
        int lrow = (r & 3) + 8 * (r >> 2) + rowhalf;
        int grow = row0 + w * 32 + lrow;
        float vals[4];
        float lm = -3.0e38f;
#pragma unroll
        for (int cs = 0; cs < 4; cs++) {
            int gcol = col0 + cs * 32 + colin;
            float v = acc[cs][r];
            if (gcol >= n || gcol == grow) v = -3.0e38f;
            vals[cs] = v;
            lm = fmaxf(lm, v);
        }
#pragma unroll
        for (int off = 1; off < 32; off <<= 1)
            lm = fmaxf(lm, __shfl_xor(lm, off));
        float ls = 0.f;
#pragma unroll
        for (int cs = 0; cs < 4; cs++)
            ls += (vals[cs] > -1.0e38f) ? expf(vals[cs] - lm) : 0.f;
#pragma unroll
        for (int off = 1; off < 32; off <<= 1) ls += __shfl_xor(ls, off);
        if (colin == 0 && grow < n)
            part[kPoff128[l] + ((b * n + grow) << lnt) + ct] =
                make_float2(lm, ls);
    }
}

// ---------------------------------------------------------------------------
// Merge partials per row: logsumexp merge, subtract cross term (bf16 inputs,
// fp32 accumulate), spread-slot atomic accumulate.
// ---------------------------------------------------------------------------
__global__ void merge_all(const unsigned short* __restrict__ zb,
                          const float2* __restrict__ part,
                          float* __restrict__ acc) {
    int wave = threadIdx.x >> 6, lane = threadIdx.x & 63;
    int row = blockIdx.x * 4 + wave;
    if (row >= NROWS_T) return;
    int l = 0;
#pragma unroll
    for (int q = 1; q <= 8; q++) l = (row >= kTRowcum[q]) ? q : l;
    int r = row - kTRowcum[l];
    int Tl = kT[l], n = 2 * Tl, nt = kNt128[l], lnt = kLog128[l];
    int b = r >> (kLogT[l] + 1);
    int rr = r & (n - 1);
    float m = -3.0e38f, s = 0.f;
    if (lane < nt) {
        float2 p = part[kPoff128[l] + ((b * n + rr) << lnt) + lane];
        m = p.x; s = p.y;
    }
    float M = m;
#pragma unroll
    for (int off = 1; off < 64; off <<= 1) M = fmaxf(M, __shfl_xor(M, off));
    float e = (lane < nt) ? s * expf(m - M) : 0.f;
#pragma unroll
    for (int off = 1; off < 64; off <<= 1) e += __shfl_xor(e, off);
    int tloc = rr & (Tl - 1);
    const unsigned short* za = zb + kZBoff[l] + (size_t)(b * Tl + tloc) * CC;
    const unsigned short* zc = zb + ZB + kZBoff[l] + (size_t)(b * Tl + tloc) * CC;
    float cs = 0.f;
#pragma unroll
    for (int j = 0; j < 5; j++)
        cs += bfu(za[lane + 64 * j]) * bfu(zc[lane + 64 * j]);
#pragma unroll
    for (int off = 1; off < 64; off <<= 1) cs += __shfl_xor(cs, off);
    if (lane == 0)
        atomicAdd(acc + (10 + l) * NSLOT + (row & (NSLOT - 1)),
                  M + logf(e) - cs);
}

__global__ void finalize_kernel(const float* __restrict__ acc,
                                float* __restrict__ out) {
    int lane = threadIdx.x;
    float loss = 0.f;
#pragma unroll
    for (int l = 0; l < 10; l++)
        loss += 0.5f / (float)(BB * kT[l]) * acc[l * NSLOT + lane];
#pragma unroll
    for (int l = 0; l < 9; l++)
        loss += 0.5f / (float)(2 * BB * kT[l]) * acc[(10 + l) * NSLOT + lane];
#pragma unroll
    for (int off = 1; off < 64; off <<= 1) loss += __shfl_xor(loss, off);
    if (lane == 0) out[0] = loss / 10.f;
}

extern "C" void kernel_launch(void* const* d_in, const int* in_sizes, int n_in,
                              void* d_out, int out_size, void* d_ws,
                              size_t ws_size, hipStream_t stream) {
    const float* z1 = (const float*)d_in[0];
    const float* z2 = (const float*)d_in[1];
    const float* t  = (const float*)d_in[2];
    float* ws = (float*)d_ws;
    unsigned short* zb = (unsigned short*)ws;
    float* tpool = ws + FT;
    float2* part = (float2*)(ws + FPART);
    float* acc = ws + FACC;  // 19*64 floats; total ws ~11.2 MB

    pool_lvl03<<<(NP1 + TTOT + 255) / 256, 256, 0, stream>>>(z1, z2, t, zb,
                                                             tpool, acc);
    pool_lvl49<<<(NP2 + 255) / 256, 256, 0, stream>>>(zb);
    topk_inst_all<<<NROWS / 4, 256, 0, stream>>>(zb, t, tpool, acc);
    temporal_mfma<<<NTBLK, 256, 0, stream>>>(zb, part);
    merge_all<<<(NROWS_T + 3) / 4, 256, 0, stream>>>(zb, part, acc);
    finalize_kernel<<<1, 64, 0, stream>>>(acc, (float*)d_out);
}

// Round 9
// 117.365 us; speedup vs baseline: 22.3545x; 1.6277x over previous
//
#include <hip/hip_runtime.h>
#include <math.h>

#define BB 8
#define CC 320
#define ZB 2618880     // per-tensor bf16 z elems, levels 0..9
#define TTOT 4088      // pooled t elems, levels 1..9 (8*511)
#define NROWS 8184     // instance rows across levels 0..9 (8*1023)
#define NROWS_T 16352  // temporal rows across levels 0..8 (16*1022)
#define NTBLK 720      // temporal 128x128 blocks across levels 0..8
#define PTOT 88032     // float2 partials total
#define NP1 327680     // stage-1 z threads: 2*8*64*320
#define NP2 5120       // stage-2 z threads: 2*8*320

// float offsets inside ws
#define FT 2618880     // pooled t (zb occupies 2*ZB ushorts = 2618880 floats)
#define FPART 2622968  // partials (float2)
#define FROW 2799032   // per-row weighted losses (NROWS + NROWS_T floats)

constexpr int kT[10]       = {512,256,128,64,32,16,8,4,2,1};
constexpr int kLogT[10]    = {9,8,7,6,5,4,3,2,1,0};
constexpr int kZBoff[10]   = {0,1310720,1966080,2293760,2457600,2539520,2580480,2600960,2611200,2616320};
constexpr int kToff[10]    = {0,0,2048,3072,3584,3840,3968,4032,4064,4080};
constexpr int kRowcum[11]  = {0,4096,6144,7168,7680,7936,8064,8128,8160,8176,8184};
constexpr int kTRowcum[10] = {0,8192,12288,14336,15360,15872,16128,16256,16320,16352};
constexpr int kTblk128[10] = {0,512,640,672,680,688,696,704,712,720};
constexpr int kNt128[9]    = {8,4,2,1,1,1,1,1,1};
constexpr int kLog128[9]   = {3,2,1,0,0,0,0,0,0};
constexpr int kPoff128[9]  = {0,65536,81920,86016,87040,87552,87808,87936,88000};

typedef short v8s __attribute__((ext_vector_type(8)));
typedef float v16f __attribute__((ext_vector_type(16)));

__device__ __forceinline__ unsigned short f2bf(float x) {
    unsigned int u = __float_as_uint(x);
    u = (u + 0x7FFFu + ((u >> 16) & 1u)) >> 16;
    return (unsigned short)u;
}
__device__ __forceinline__ float bfu(unsigned short u) {
    return __uint_as_float(((unsigned int)u) << 16);
}

// ---------------------------------------------------------------------------
// Stage 1: fused level-0 bf16 convert + bf16 max-pool levels 1..3 + fp32
// t-pool (all levels).
// ---------------------------------------------------------------------------
__global__ void pool_lvl03(const float* __restrict__ z1,
                           const float* __restrict__ z2,
                           const float* __restrict__ t,
                           unsigned short* __restrict__ zb,
                           float* __restrict__ tpool) {
    int gid = blockIdx.x * 256 + threadIdx.x;
    if (gid < NP1) {
        int c = gid % CC;
        int rest = gid / CC;
        int ch = rest & 63;
        int b = (rest >> 6) & 7;
        int which = rest >> 9;
        const float* src =
            (which ? z2 : z1) + ((size_t)(b * 512 + ch * 8)) * CC + c;
        unsigned short* dst = zb + (size_t)which * ZB;
        float v[8];
#pragma unroll
        for (int j = 0; j < 8; j++) v[j] = src[(size_t)j * CC];
#pragma unroll
        for (int j = 0; j < 8; j++)
            dst[(size_t)(b * 512 + ch * 8 + j) * CC + c] = f2bf(v[j]);
        float m1[4];
#pragma unroll
        for (int j = 0; j < 4; j++) m1[j] = fmaxf(v[2 * j], v[2 * j + 1]);
#pragma unroll
        for (int j = 0; j < 4; j++)
            dst[kZBoff[1] + (size_t)(b * 256 + ch * 4 + j) * CC + c] =
                f2bf(m1[j]);
        float m2[2] = {fmaxf(m1[0], m1[1]), fmaxf(m1[2], m1[3])};
#pragma unroll
        for (int j = 0; j < 2; j++)
            dst[kZBoff[2] + (size_t)(b * 128 + ch * 2 + j) * CC + c] =
                f2bf(m2[j]);
        dst[kZBoff[3] + (size_t)(b * 64 + ch) * CC + c] =
            f2bf(fmaxf(m2[0], m2[1]));
    } else if (gid < NP1 + TTOT) {
        int i = gid - NP1;
        int l = 1;
#pragma unroll
        for (int q = 2; q <= 9; q++) l = (i >= kToff[q]) ? q : l;
        int rem = i - kToff[l];
        int Tl = kT[l];
        int t2 = rem & (Tl - 1);
        int b = rem >> kLogT[l];
        int win = 512 / Tl;
        const float* p = t + b * 512 + t2 * win;
        float s = 0.f;
        for (int j = 0; j < win; j++) s += p[j];
        tpool[kToff[l] + rem] = s * (1.0f / win);
    }
}

// ---------------------------------------------------------------------------
// Stage 2: bf16 max-pool levels 4..9 from level 3.
// ---------------------------------------------------------------------------
__global__ void pool_lvl49(unsigned short* __restrict__ zb) {
    int gid = blockIdx.x * 256 + threadIdx.x;
    if (gid >= NP2) return;
    int c = gid % CC;
    int r2 = gid / CC;
    int b = r2 & 7;
    int which = r2 >> 3;
    unsigned short* base = zb + (size_t)which * ZB;
    const unsigned short* src = base + kZBoff[3] + (size_t)(b * 64) * CC + c;
    float a[32];
#pragma unroll
    for (int j = 0; j < 32; j++)
        a[j] = fmaxf(bfu(src[(size_t)(2 * j) * CC]),
                     bfu(src[(size_t)(2 * j + 1) * CC]));
#pragma unroll
    for (int j = 0; j < 32; j++)
        base[kZBoff[4] + (size_t)(b * 32 + j) * CC + c] = f2bf(a[j]);
#pragma unroll
    for (int j = 0; j < 16; j++) a[j] = fmaxf(a[2 * j], a[2 * j + 1]);
#pragma unroll
    for (int j = 0; j < 16; j++)
        base[kZBoff[5] + (size_t)(b * 16 + j) * CC + c] = f2bf(a[j]);
#pragma unroll
    for (int j = 0; j < 8; j++) a[j] = fmaxf(a[2 * j], a[2 * j + 1]);
#pragma unroll
    for (int j = 0; j < 8; j++)
        base[kZBoff[6] + (size_t)(b * 8 + j) * CC + c] = f2bf(a[j]);
#pragma unroll
    for (int j = 0; j < 4; j++) a[j] = fmaxf(a[2 * j], a[2 * j + 1]);
#pragma unroll
    for (int j = 0; j < 4; j++)
        base[kZBoff[7] + (size_t)(b * 4 + j) * CC + c] = f2bf(a[j]);
#pragma unroll
    for (int j = 0; j < 2; j++) a[j] = fmaxf(a[2 * j], a[2 * j + 1]);
#pragma unroll
    for (int j = 0; j < 2; j++)
        base[kZBoff[8] + (size_t)(b * 2 + j) * CC + c] = f2bf(a[j]);
    base[kZBoff[9] + (size_t)b * CC + c] = f2bf(fmaxf(a[0], a[1]));
}

// ---------------------------------------------------------------------------
// Fused top-8 + instance loss, one 64-lane wave per row; weighted row loss
// stored to a dedicated slot (no atomics).
// ---------------------------------------------------------------------------
__global__ void topk_inst_all(const unsigned short* __restrict__ zb,
                              const float* __restrict__ t0,
                              const float* __restrict__ tpool,
                              float* __restrict__ rowloss) {
    int wave = threadIdx.x >> 6, lane = threadIdx.x & 63;
    int row = blockIdx.x * 4 + wave;
    if (row >= NROWS) return;
    int l = 0;
#pragma unroll
    for (int q = 1; q <= 9; q++) l = (row >= kRowcum[q]) ? q : l;
    int n = row - kRowcum[l];
    int T = kT[l];
    const float* tt = l ? tpool + kToff[l] : t0;
    int seq = n >> kLogT[l];
    float tn = tt[n];

    int idx8[8];
    if (lane < 8) {
        const float* ts = tt + lane * T;
        bool own = (lane == seq);
        int lo = 0, hi = T;
        while (lo < hi) {
            int mid = (lo + hi) >> 1;
            if (ts[mid] < tn) lo = mid + 1; else hi = mid;
        }
        int il = lo - 1, ih = lo;
        float dl = (il >= 0) ? (tn - ts[il]) : 3.0e38f;
        float dh = (ih < T) ? (ts[ih] - tn) : 3.0e38f;
#pragma unroll
        for (int r = 0; r < 8; r++) {
            bool pickLo = (dl <= dh);
            float dmin = own ? 1.0e12f : (pickLo ? dl : dh);
            int midx = own ? n : (lane * T + (pickLo ? il : ih));
            unsigned long long key =
                ((unsigned long long)__float_as_uint(dmin) << 32) |
                (unsigned int)midx;
            unsigned long long o;
            o = __shfl_xor(key, 1); key = (key < o) ? key : o;
            o = __shfl_xor(key, 2); key = (key < o) ? key : o;
            o = __shfl_xor(key, 4); key = (key < o) ? key : o;
            int widx = (int)(unsigned int)(key & 0xffffffffull);
            idx8[r] = widx;
            if (!own && widx == midx) {
                if (pickLo) { il--; dl = (il >= 0) ? (tn - ts[il]) : 3.0e38f; }
                else        { ih++; dh = (ih < T)  ? (ts[ih] - tn) : 3.0e38f; }
            }
        }
    }

    const unsigned short* z1 = zb + kZBoff[l];
    const unsigned short* z2 = zb + ZB + kZBoff[l];
    const unsigned short* z1n = z1 + (size_t)n * CC;
    const unsigned short* z2n = z2 + (size_t)n * CC;
    float a[5];
#pragma unroll
    for (int j = 0; j < 5; j++) a[j] = bfu(z1n[lane + 64 * j]);
    float part[17];
    {
        float s = 0.f;
#pragma unroll
        for (int j = 0; j < 5; j++) s += a[j] * bfu(z2n[lane + 64 * j]);
        part[0] = s;
    }
#pragma unroll
    for (int k = 0; k < 8; k++) {
        int p = __shfl(idx8[k], 0);
        const unsigned short* r1 = z1 + (size_t)p * CC;
        const unsigned short* r2 = z2 + (size_t)p * CC;
        float s1 = 0.f, s2 = 0.f;
#pragma unroll
        for (int j = 0; j < 5; j++) {
            float av = a[j];
            s1 += av * bfu(r1[lane + 64 * j]);
            s2 += av * bfu(r2[lane + 64 * j]);
        }
        part[1 + k] = s1;
        part[9 + k] = s2;
    }
#pragma unroll
    for (int q = 0; q < 17; q++) {
        float v = part[q];
        for (int off = 32; off > 0; off >>= 1) v += __shfl_xor(v, off);
        part[q] = v;
    }
    if (lane == 0) {
        float m = part[0];
#pragma unroll
        for (int q = 1; q < 17; q++) m = fmaxf(m, part[q]);
        float s = 0.f;
#pragma unroll
        for (int q = 0; q < 17; q++) s += expf(part[q] - m);
        float w = 0.05f / (float)(BB * T);   // alpha/(B*T)/10
        rowloss[row] = w * (m + logf(s) - part[0]);
    }
}

// ---------------------------------------------------------------------------
// Temporal via bf16 MFMA: 128x128 block tile, 4 waves x (32 rows x 128 cols),
// mfma_f32_32x32x16_bf16, K staged 32 at a time in a lane-linear LDS layout.
// Per-row masked (max, sumexp) partial written per col-tile.
// ---------------------------------------------------------------------------
__global__ void __launch_bounds__(256) temporal_mfma(
        const unsigned short* __restrict__ zb, float2* __restrict__ part) {
    int bid = blockIdx.x;
    int l = 0;
#pragma unroll
    for (int q = 1; q <= 8; q++) l = (bid >= kTblk128[q]) ? q : l;
    int rem = bid - kTblk128[l];
    int Tl = kT[l], n = 2 * Tl, nt = kNt128[l], lnt = kLog128[l];
    int ct = rem & (nt - 1);
    int rt = (rem >> lnt) & (nt - 1);
    int b = rem >> (2 * lnt);
    const unsigned short* zb1 = zb + kZBoff[l] + (size_t)b * Tl * CC;
    const unsigned short* zb2 = zb + ZB + kZBoff[l] + (size_t)b * Tl * CC;
    int row0 = rt * 128, col0 = ct * 128;
    int tid = threadIdx.x;
    int w = tid >> 6, lane = tid & 63;
    __shared__ __align__(16) unsigned short As[4096];
    __shared__ __align__(16) unsigned short Bs[4096];

    v16f acc[4];
#pragma unroll
    for (int cs = 0; cs < 4; cs++)
#pragma unroll
        for (int e = 0; e < 16; e++) acc[cs][e] = 0.f;

    int sofq[2]; const unsigned short* srcA[2]; const unsigned short* srcB[2];
    bool vA[2], vB[2];
#pragma unroll
    for (int q = 0; q < 2; q++) {
        int g = q * 256 + tid;
        int r = g & 127, kbb = g >> 7;
        sofq[q] = (r >> 5) * 1024 + (kbb >> 1) * 512 + (kbb & 1) * 256 +
                  (r & 31) * 8;
        int ka = kbb * 8;
        int gr = row0 + r;
        vA[q] = gr < n;
        srcA[q] = vA[q] ? ((gr < Tl) ? zb1 + (size_t)gr * CC + ka
                                     : zb2 + (size_t)(gr - Tl) * CC + ka)
                        : zb1;
        int gc = col0 + r;
        vB[q] = gc < n;
        srcB[q] = vB[q] ? ((gc < Tl) ? zb1 + (size_t)gc * CC + ka
                                     : zb2 + (size_t)(gc - Tl) * CC + ka)
                        : zb1;
    }

    for (int kc = 0; kc < CC; kc += 32) {
#pragma unroll
        for (int q = 0; q < 2; q++) {
            uint4 av = vA[q] ? *(const uint4*)(srcA[q] + kc)
                             : make_uint4(0, 0, 0, 0);
            uint4 bv = vB[q] ? *(const uint4*)(srcB[q] + kc)
                             : make_uint4(0, 0, 0, 0);
            *(uint4*)(As + sofq[q]) = av;
            *(uint4*)(Bs + sofq[q]) = bv;
        }
        __syncthreads();
        const unsigned short* Ab = As + w * 1024;
#pragma unroll
        for (int cc = 0; cc < 2; cc++) {
            v8s af = *(const v8s*)(Ab + cc * 512 + lane * 8);
#pragma unroll
            for (int cs = 0; cs < 4; cs++) {
                v8s bf = *(const v8s*)(Bs + cs * 1024 + cc * 512 + lane * 8);
                acc[cs] = __builtin_amdgcn_mfma_f32_32x32x16_bf16(
                    af, bf, acc[cs], 0, 0, 0);
            }
        }
        __syncthreads();
    }

    int colin = lane & 31;
    int rowhalf = 4 * (lane >> 5);
#pragma unroll
    for (int r = 0; r < 16; r++) {
        int lrow = (r & 3) + 8 * (r >> 2) + rowhalf;
        int grow = row0 + w * 32 + lrow;
        float vals[4];
        float lm = -3.0e38f;
#pragma unroll
        for (int cs = 0; cs < 4; cs++) {
            int gcol = col0 + cs * 32 + colin;
            float v = acc[cs][r];
            if (gcol >= n || gcol == grow) v = -3.0e38f;
            vals[cs] = v;
            lm = fmaxf(lm, v);
        }
#pragma unroll
        for (int off = 1; off < 32; off <<= 1)
            lm = fmaxf(lm, __shfl_xor(lm, off));
        float ls = 0.f;
#pragma unroll
        for (int cs = 0; cs < 4; cs++)
            ls += (vals[cs] > -1.0e38f) ? expf(vals[cs] - lm) : 0.f;
#pragma unroll
        for (int off = 1; off < 32; off <<= 1) ls += __shfl_xor(ls, off);
        if (colin == 0 && grow < n)
            part[kPoff128[l] + ((b * n + grow) << lnt) + ct] =
                make_float2(lm, ls);
    }
}

// ---------------------------------------------------------------------------
// Merge partials per row: logsumexp merge, subtract cross term; weighted row
// loss stored to a dedicated slot (no atomics).
// ---------------------------------------------------------------------------
__global__ void merge_all(const unsigned short* __restrict__ zb,
                          const float2* __restrict__ part,
                          float* __restrict__ rowloss) {
    int wave = threadIdx.x >> 6, lane = threadIdx.x & 63;
    int row = blockIdx.x * 4 + wave;
    if (row >= NROWS_T) return;
    int l = 0;
#pragma unroll
    for (int q = 1; q <= 8; q++) l = (row >= kTRowcum[q]) ? q : l;
    int r = row - kTRowcum[l];
    int Tl = kT[l], n = 2 * Tl, nt = kNt128[l], lnt = kLog128[l];
    int b = r >> (kLogT[l] + 1);
    int rr = r & (n - 1);
    float m = -3.0e38f, s = 0.f;
    if (lane < nt) {
        float2 p = part[kPoff128[l] + ((b * n + rr) << lnt) + lane];
        m = p.x; s = p.y;
    }
    float M = m;
#pragma unroll
    for (int off = 1; off < 64; off <<= 1) M = fmaxf(M, __shfl_xor(M, off));
    float e = (lane < nt) ? s * expf(m - M) : 0.f;
#pragma unroll
    for (int off = 1; off < 64; off <<= 1) e += __shfl_xor(e, off);
    int tloc = rr & (Tl - 1);
    const unsigned short* za = zb + kZBoff[l] + (size_t)(b * Tl + tloc) * CC;
    const unsigned short* zc = zb + ZB + kZBoff[l] + (size_t)(b * Tl + tloc) * CC;
    float cs = 0.f;
#pragma unroll
    for (int j = 0; j < 5; j++)
        cs += bfu(za[lane + 64 * j]) * bfu(zc[lane + 64 * j]);
#pragma unroll
    for (int off = 1; off < 64; off <<= 1) cs += __shfl_xor(cs, off);
    if (lane == 0) {
        float w = 0.025f / (float)(BB * Tl);  // (1-alpha)/(2*B*T)/10
        rowloss[NROWS + row] = w * (M + logf(e) - cs);
    }
}

// ---------------------------------------------------------------------------
// Final flat sum of all weighted row losses -> out[0]. Single block, direct
// store (replay-safe: no accumulation into d_out).
// ---------------------------------------------------------------------------
__global__ void reduce_kernel(const float* __restrict__ rowloss,
                              float* __restrict__ out) {
    __shared__ float sm[16];
    int tid = threadIdx.x;
    float s = 0.f;
    for (int i = tid; i < NROWS + NROWS_T; i += 1024) s += rowloss[i];
#pragma unroll
    for (int off = 32; off > 0; off >>= 1) s += __shfl_xor(s, off);
    if ((tid & 63) == 0) sm[tid >> 6] = s;
    __syncthreads();
    if (tid < 64) {
        float v = (tid < 16) ? sm[tid] : 0.f;
#pragma unroll
        for (int off = 8; off > 0; off >>= 1) v += __shfl_xor(v, off);
        if (tid == 0) out[0] = v;
    }
}

extern "C" void kernel_launch(void* const* d_in, const int* in_sizes, int n_in,
                              void* d_out, int out_size, void* d_ws,
                              size_t ws_size, hipStream_t stream) {
    const float* z1 = (const float*)d_in[0];
    const float* z2 = (const float*)d_in[1];
    const float* t  = (const float*)d_in[2];
    float* ws = (float*)d_ws;
    unsigned short* zb = (unsigned short*)ws;
    float* tpool = ws + FT;
    float2* part = (float2*)(ws + FPART);
    float* rowloss = ws + FROW;  // 24536 floats; total ws ~11.3 MB

    pool_lvl03<<<(NP1 + TTOT + 255) / 256, 256, 0, stream>>>(z1, z2, t, zb,
                                                             tpool);
    pool_lvl49<<<(NP2 + 255) / 256, 256, 0, stream>>>(zb);
    topk_inst_all<<<NROWS / 4, 256, 0, stream>>>(zb, t, tpool, rowloss);
    temporal_mfma<<<NTBLK, 256, 0, stream>>>(zb, part);
    merge_all<<<(NROWS_T + 3) / 4, 256, 0, stream>>>(zb, part, rowloss);
    reduce_kernel<<<1, 1024, 0, stream>>>(rowloss, (float*)d_out);
}

// Round 10
// 116.000 us; speedup vs baseline: 22.6176x; 1.0118x over previous
//
#include <hip/hip_runtime.h>
#include <math.h>

#define BB 8
#define CC 320
#define ZB 2618880     // per-tensor bf16 z elems, levels 0..9
#define TTOT 4088      // pooled t elems, levels 1..9 (8*511)
#define NROWS 8184     // instance rows across levels 0..9 (8*1023)
#define NROWS_T 16352  // temporal rows across levels 0..8 (16*1022)
#define NTBLK 440      // symmetric temporal tiles across levels 0..8
#define PTOT 88032     // float2 partials total
#define XTOT 8176      // cross-term floats total
#define NP1 327680     // stage-1 z threads: 2*8*64*320
#define NP2 5120       // stage-2 z threads: 2*8*320

// float offsets inside ws
#define FT 2618880     // pooled t (zb occupies 2*ZB ushorts = 2618880 floats)
#define FPART 2622968  // partials (float2)
#define FROW 2799032   // per-row weighted losses (NROWS + NROWS_T floats)
#define FCROSS 2823568 // cross terms (XTOT floats)

constexpr int kT[10]       = {512,256,128,64,32,16,8,4,2,1};
constexpr int kLogT[10]    = {9,8,7,6,5,4,3,2,1,0};
constexpr int kZBoff[10]   = {0,1310720,1966080,2293760,2457600,2539520,2580480,2600960,2611200,2616320};
constexpr int kToff[10]    = {0,0,2048,3072,3584,3840,3968,4032,4064,4080};
constexpr int kRowcum[11]  = {0,4096,6144,7168,7680,7936,8064,8128,8160,8176,8184};
constexpr int kTRowcum[10] = {0,8192,12288,14336,15360,15872,16128,16256,16320,16352};
constexpr int kNt128[9]    = {8,4,2,1,1,1,1,1,1};
constexpr int kLog128[9]   = {3,2,1,0,0,0,0,0,0};
constexpr int kPoff128[9]  = {0,65536,81920,86016,87040,87552,87808,87936,88000};
constexpr int kScount[9]   = {36,10,3,1,1,1,1,1,1};       // upper-tri tiles/batch
constexpr int kSblkcum[10] = {0,288,368,392,400,408,416,424,432,440};
constexpr int kXoff[9]     = {0,4096,6144,7168,7680,7936,8064,8128,8160};

typedef short v8s __attribute__((ext_vector_type(8)));
typedef float v16f __attribute__((ext_vector_type(16)));

__device__ __forceinline__ unsigned short f2bf(float x) {
    unsigned int u = __float_as_uint(x);
    u = (u + 0x7FFFu + ((u >> 16) & 1u)) >> 16;
    return (unsigned short)u;
}
__device__ __forceinline__ float bfu(unsigned short u) {
    return __uint_as_float(((unsigned int)u) << 16);
}

// ---------------------------------------------------------------------------
// Stage 1: fused level-0 bf16 convert + bf16 max-pool levels 1..3 + fp32
// t-pool (all levels).
// ---------------------------------------------------------------------------
__global__ void pool_lvl03(const float* __restrict__ z1,
                           const float* __restrict__ z2,
                           const float* __restrict__ t,
                           unsigned short* __restrict__ zb,
                           float* __restrict__ tpool) {
    int gid = blockIdx.x * 256 + threadIdx.x;
    if (gid < NP1) {
        int c = gid % CC;
        int rest = gid / CC;
        int ch = rest & 63;
        int b = (rest >> 6) & 7;
        int which = rest >> 9;
        const float* src =
            (which ? z2 : z1) + ((size_t)(b * 512 + ch * 8)) * CC + c;
        unsigned short* dst = zb + (size_t)which * ZB;
        float v[8];
#pragma unroll
        for (int j = 0; j < 8; j++) v[j] = src[(size_t)j * CC];
#pragma unroll
        for (int j = 0; j < 8; j++)
            dst[(size_t)(b * 512 + ch * 8 + j) * CC + c] = f2bf(v[j]);
        float m1[4];
#pragma unroll
        for (int j = 0; j < 4; j++) m1[j] = fmaxf(v[2 * j], v[2 * j + 1]);
#pragma unroll
        for (int j = 0; j < 4; j++)
            dst[kZBoff[1] + (size_t)(b * 256 + ch * 4 + j) * CC + c] =
                f2bf(m1[j]);
        float m2[2] = {fmaxf(m1[0], m1[1]), fmaxf(m1[2], m1[3])};
#pragma unroll
        for (int j = 0; j < 2; j++)
            dst[kZBoff[2] + (size_t)(b * 128 + ch * 2 + j) * CC + c] =
                f2bf(m2[j]);
        dst[kZBoff[3] + (size_t)(b * 64 + ch) * CC + c] =
            f2bf(fmaxf(m2[0], m2[1]));
    } else if (gid < NP1 + TTOT) {
        int i = gid - NP1;
        int l = 1;
#pragma unroll
        for (int q = 2; q <= 9; q++) l = (i >= kToff[q]) ? q : l;
        int rem = i - kToff[l];
        int Tl = kT[l];
        int t2 = rem & (Tl - 1);
        int b = rem >> kLogT[l];
        int win = 512 / Tl;
        const float* p = t + b * 512 + t2 * win;
        float s = 0.f;
        for (int j = 0; j < win; j++) s += p[j];
        tpool[kToff[l] + rem] = s * (1.0f / win);
    }
}

// ---------------------------------------------------------------------------
// Stage 2: bf16 max-pool levels 4..9 from level 3.
// ---------------------------------------------------------------------------
__global__ void pool_lvl49(unsigned short* __restrict__ zb) {
    int gid = blockIdx.x * 256 + threadIdx.x;
    if (gid >= NP2) return;
    int c = gid % CC;
    int r2 = gid / CC;
    int b = r2 & 7;
    int which = r2 >> 3;
    unsigned short* base = zb + (size_t)which * ZB;
    const unsigned short* src = base + kZBoff[3] + (size_t)(b * 64) * CC + c;
    float a[32];
#pragma unroll
    for (int j = 0; j < 32; j++)
        a[j] = fmaxf(bfu(src[(size_t)(2 * j) * CC]),
                     bfu(src[(size_t)(2 * j + 1) * CC]));
#pragma unroll
    for (int j = 0; j < 32; j++)
        base[kZBoff[4] + (size_t)(b * 32 + j) * CC + c] = f2bf(a[j]);
#pragma unroll
    for (int j = 0; j < 16; j++) a[j] = fmaxf(a[2 * j], a[2 * j + 1]);
#pragma unroll
    for (int j = 0; j < 16; j++)
        base[kZBoff[5] + (size_t)(b * 16 + j) * CC + c] = f2bf(a[j]);
#pragma unroll
    for (int j = 0; j < 8; j++) a[j] = fmaxf(a[2 * j], a[2 * j + 1]);
#pragma unroll
    for (int j = 0; j < 8; j++)
        base[kZBoff[6] + (size_t)(b * 8 + j) * CC + c] = f2bf(a[j]);
#pragma unroll
    for (int j = 0; j < 4; j++) a[j] = fmaxf(a[2 * j], a[2 * j + 1]);
#pragma unroll
    for (int j = 0; j < 4; j++)
        base[kZBoff[7] + (size_t)(b * 4 + j) * CC + c] = f2bf(a[j]);
#pragma unroll
    for (int j = 0; j < 2; j++) a[j] = fmaxf(a[2 * j], a[2 * j + 1]);
#pragma unroll
    for (int j = 0; j < 2; j++)
        base[kZBoff[8] + (size_t)(b * 2 + j) * CC + c] = f2bf(a[j]);
    base[kZBoff[9] + (size_t)b * CC + c] = f2bf(fmaxf(a[0], a[1]));
}

// ---------------------------------------------------------------------------
// Fused top-8 + instance loss, one 64-lane wave per row; weighted row loss
// stored to a dedicated slot (no atomics).
// ---------------------------------------------------------------------------
__global__ void topk_inst_all(const unsigned short* __restrict__ zb,
                              const float* __restrict__ t0,
                              const float* __restrict__ tpool,
                              float* __restrict__ rowloss) {
    int wave = threadIdx.x >> 6, lane = threadIdx.x & 63;
    int row = blockIdx.x * 4 + wave;
    if (row >= NROWS) return;
    int l = 0;
#pragma unroll
    for (int q = 1; q <= 9; q++) l = (row >= kRowcum[q]) ? q : l;
    int n = row - kRowcum[l];
    int T = kT[l];
    const float* tt = l ? tpool + kToff[l] : t0;
    int seq = n >> kLogT[l];
    float tn = tt[n];

    int idx8[8];
    if (lane < 8) {
        const float* ts = tt + lane * T;
        bool own = (lane == seq);
        int lo = 0, hi = T;
        while (lo < hi) {
            int mid = (lo + hi) >> 1;
            if (ts[mid] < tn) lo = mid + 1; else hi = mid;
        }
        int il = lo - 1, ih = lo;
        float dl = (il >= 0) ? (tn - ts[il]) : 3.0e38f;
        float dh = (ih < T) ? (ts[ih] - tn) : 3.0e38f;
#pragma unroll
        for (int r = 0; r < 8; r++) {
            bool pickLo = (dl <= dh);
            float dmin = own ? 1.0e12f : (pickLo ? dl : dh);
            int midx = own ? n : (lane * T + (pickLo ? il : ih));
            unsigned long long key =
                ((unsigned long long)__float_as_uint(dmin) << 32) |
                (unsigned int)midx;
            unsigned long long o;
            o = __shfl_xor(key, 1); key = (key < o) ? key : o;
            o = __shfl_xor(key, 2); key = (key < o) ? key : o;
            o = __shfl_xor(key, 4); key = (key < o) ? key : o;
            int widx = (int)(unsigned int)(key & 0xffffffffull);
            idx8[r] = widx;
            if (!own && widx == midx) {
                if (pickLo) { il--; dl = (il >= 0) ? (tn - ts[il]) : 3.0e38f; }
                else        { ih++; dh = (ih < T)  ? (ts[ih] - tn) : 3.0e38f; }
            }
        }
    }

    const unsigned short* z1 = zb + kZBoff[l];
    const unsigned short* z2 = zb + ZB + kZBoff[l];
    const unsigned short* z1n = z1 + (size_t)n * CC;
    const unsigned short* z2n = z2 + (size_t)n * CC;
    float a[5];
#pragma unroll
    for (int j = 0; j < 5; j++) a[j] = bfu(z1n[lane + 64 * j]);
    float part[17];
    {
        float s = 0.f;
#pragma unroll
        for (int j = 0; j < 5; j++) s += a[j] * bfu(z2n[lane + 64 * j]);
        part[0] = s;
    }
#pragma unroll
    for (int k = 0; k < 8; k++) {
        int p = __shfl(idx8[k], 0);
        const unsigned short* r1 = z1 + (size_t)p * CC;
        const unsigned short* r2 = z2 + (size_t)p * CC;
        float s1 = 0.f, s2 = 0.f;
#pragma unroll
        for (int j = 0; j < 5; j++) {
            float av = a[j];
            s1 += av * bfu(r1[lane + 64 * j]);
            s2 += av * bfu(r2[lane + 64 * j]);
        }
        part[1 + k] = s1;
        part[9 + k] = s2;
    }
#pragma unroll
    for (int q = 0; q < 17; q++) {
        float v = part[q];
        for (int off = 32; off > 0; off >>= 1) v += __shfl_xor(v, off);
        part[q] = v;
    }
    if (lane == 0) {
        float m = part[0];
#pragma unroll
        for (int q = 1; q < 17; q++) m = fmaxf(m, part[q]);
        float s = 0.f;
#pragma unroll
        for (int q = 0; q < 17; q++) s += expf(part[q] - m);
        float w = 0.05f / (float)(BB * T);   // alpha/(B*T)/10
        rowloss[row] = w * (m + logf(s) - part[0]);
    }
}

// ---------------------------------------------------------------------------
// Temporal via bf16 MFMA, SYMMETRIC tiling (ct >= rt only). Off-diagonal
// tiles emit row-partials (slot ct) AND col-partials (slot rt, via LDS
// 4-wave combine). The tile with ct-rt == T>>7 also extracts the cross term
// sim[row,row+T] from its acc registers into crossbuf.
// ---------------------------------------------------------------------------
__global__ void __launch_bounds__(256) temporal_mfma(
        const unsigned short* __restrict__ zb, float2* __restrict__ part,
        float* __restrict__ crossbuf) {
    int bid = blockIdx.x;
    int l = 0;
#pragma unroll
    for (int q = 1; q <= 8; q++) l = (bid >= kSblkcum[q]) ? q : l;
    int rem = bid - kSblkcum[l];
    int cnt = kScount[l];
    int Tl = kT[l], n = 2 * Tl, lnt = kLog128[l];
    int b = rem / cnt;
    int pr = rem - b * cnt;
    int rt = 0, width = kNt128[l];
    while (pr >= width) { pr -= width; rt++; width--; }
    int ct = rt + pr;
    bool diag = (rt == ct);
    const unsigned short* zb1 = zb + kZBoff[l] + (size_t)b * Tl * CC;
    const unsigned short* zb2 = zb + ZB + kZBoff[l] + (size_t)b * Tl * CC;
    int row0 = rt * 128, col0 = ct * 128;
    int tid = threadIdx.x;
    int w = tid >> 6, lane = tid & 63;
    __shared__ __align__(16) unsigned short As[4096];
    __shared__ __align__(16) unsigned short Bs[4096];
    __shared__ float2 cred[4][128];

    v16f acc[4];
#pragma unroll
    for (int cs = 0; cs < 4; cs++)
#pragma unroll
        for (int e = 0; e < 16; e++) acc[cs][e] = 0.f;

    int sofq[2]; const unsigned short* srcA[2]; const unsigned short* srcB[2];
    bool vA[2], vB[2];
#pragma unroll
    for (int q = 0; q < 2; q++) {
        int g = q * 256 + tid;
        int r = g & 127, kbb = g >> 7;
        sofq[q] = (r >> 5) * 1024 + (kbb >> 1) * 512 + (kbb & 1) * 256 +
                  (r & 31) * 8;
        int ka = kbb * 8;
        int gr = row0 + r;
        vA[q] = gr < n;
        srcA[q] = vA[q] ? ((gr < Tl) ? zb1 + (size_t)gr * CC + ka
                                     : zb2 + (size_t)(gr - Tl) * CC + ka)
                        : zb1;
        int gc = col0 + r;
        vB[q] = gc < n;
        srcB[q] = vB[q] ? ((gc < Tl) ? zb1 + (size_t)gc * CC + ka
                                     : zb2 + (size_t)(gc - Tl) * CC + ka)
                        : zb1;
    }

    for (int kc = 0; kc < CC; kc += 32) {
#pragma unroll
        for (int q = 0; q < 2; q++) {
            uint4 av = vA[q] ? *(const uint4*)(srcA[q] + kc)
                             : make_uint4(0, 0, 0, 0);
            *(uint4*)(As + sofq[q]) = av;
            if (!diag) {
                uint4 bv = vB[q] ? *(const uint4*)(srcB[q] + kc)
                                 : make_uint4(0, 0, 0, 0);
                *(uint4*)(Bs + sofq[q]) = bv;
            }
        }
        __syncthreads();
        const unsigned short* Ab = As + w * 1024;
        const unsigned short* Bb = diag ? As : Bs;
#pragma unroll
        for (int cc = 0; cc < 2; cc++) {
            v8s af = *(const v8s*)(Ab + cc * 512 + lane * 8);
#pragma unroll
            for (int cs = 0; cs < 4; cs++) {
                v8s bf = *(const v8s*)(Bb + cs * 1024 + cc * 512 + lane * 8);
                acc[cs] = __builtin_amdgcn_mfma_f32_32x32x16_bf16(
                    af, bf, acc[cs], 0, 0, 0);
            }
        }
        __syncthreads();
    }

    int colin = lane & 31;
    int rowhalf = 4 * (lane >> 5);

    // row pass (masking only bites on diagonal / padded tiles)
#pragma unroll
    for (int r = 0; r < 16; r++) {
        int lrow = (r & 3) + 8 * (r >> 2) + rowhalf;
        int grow = row0 + w * 32 + lrow;
        float vals[4];
        float lm = -3.0e38f;
#pragma unroll
        for (int cs = 0; cs < 4; cs++) {
            int gcol = col0 + cs * 32 + colin;
            float v = acc[cs][r];
            if (gcol >= n || gcol == grow) v = -3.0e38f;
            vals[cs] = v;
            lm = fmaxf(lm, v);
        }
#pragma unroll
        for (int off = 1; off < 32; off <<= 1)
            lm = fmaxf(lm, __shfl_xor(lm, off));
        float ls = 0.f;
#pragma unroll
        for (int cs = 0; cs < 4; cs++)
            ls += (vals[cs] > -1.0e38f) ? expf(vals[cs] - lm) : 0.f;
#pragma unroll
        for (int off = 1; off < 32; off <<= 1) ls += __shfl_xor(ls, off);
        if (colin == 0 && grow < n)
            part[kPoff128[l] + ((b * n + grow) << lnt) + ct] =
                make_float2(lm, ls);
    }

    // cross extraction: tile containing sim[row, row+T] columns
    if (ct - rt == (Tl >> 7)) {
#pragma unroll
        for (int r = 0; r < 16; r++) {
            int lrow = (r & 3) + 8 * (r >> 2) + rowhalf;
            int grow = row0 + w * 32 + lrow;
            if (grow < Tl) {
                int cidx = grow + Tl - col0;
                int cs_p = cidx >> 5, colin_p = cidx & 31;
                float cand = 0.f;
#pragma unroll
                for (int cs = 0; cs < 4; cs++)
                    cand += (cs == cs_p && colin == colin_p) ? acc[cs][r] : 0.f;
#pragma unroll
                for (int off = 1; off < 32; off <<= 1)
                    cand += __shfl_xor(cand, off);
                if (colin == 0)
                    crossbuf[kXoff[l] + b * Tl + grow] = cand;
            }
        }
    }

    // col pass (off-diagonal tiles only; all elements valid, no masking)
    if (!diag) {
#pragma unroll
        for (int cs = 0; cs < 4; cs++) {
            float m = acc[cs][0];
#pragma unroll
            for (int r = 1; r < 16; r++) m = fmaxf(m, acc[cs][r]);
            float mo = __shfl_xor(m, 32);
            float mm = fmaxf(m, mo);
            float s = 0.f;
#pragma unroll
            for (int r = 0; r < 16; r++) s += expf(acc[cs][r] - mm);
            s += __shfl_xor(s, 32);
            if (lane < 32) cred[w][cs * 32 + lane] = make_float2(mm, s);
        }
    }
    __syncthreads();
    if (!diag && tid < 128) {
        float2 a0 = cred[0][tid], a1 = cred[1][tid];
        float2 a2 = cred[2][tid], a3 = cred[3][tid];
        float M = fmaxf(fmaxf(a0.x, a1.x), fmaxf(a2.x, a3.x));
        float S = a0.y * expf(a0.x - M) + a1.y * expf(a1.x - M) +
                  a2.y * expf(a2.x - M) + a3.y * expf(a3.x - M);
        int gcol = col0 + tid;
        part[kPoff128[l] + ((b * n + gcol) << lnt) + rt] = make_float2(M, S);
    }
}

// ---------------------------------------------------------------------------
// Merge partials per row, one THREAD per row: online-lse merge of <=8
// partials + precomputed cross term; weighted row loss store (no atomics).
// ---------------------------------------------------------------------------
__global__ void merge_all(const float2* __restrict__ part,
                          const float* __restrict__ crossbuf,
                          float* __restrict__ rowloss) {
    int row = blockIdx.x * 256 + threadIdx.x;
    if (row >= NROWS_T) return;
    int l = 0;
#pragma unroll
    for (int q = 1; q <= 8; q++) l = (row >= kTRowcum[q]) ? q : l;
    int r = row - kTRowcum[l];
    int Tl = kT[l], n = 2 * Tl, nt = kNt128[l], lnt = kLog128[l];
    int b = r >> (kLogT[l] + 1);
    int rr = r & (n - 1);
    const float2* p = part + kPoff128[l] + ((size_t)(b * n + rr) << lnt);
    float M = -3.0e38f, S = 0.f;
    for (int k = 0; k < nt; k++) {
        float2 q = p[k];
        float nM = fmaxf(M, q.x);
        S = S * expf(M - nM) + q.y * expf(q.x - nM);
        M = nM;
    }
    float cross = crossbuf[kXoff[l] + b * Tl + (rr < Tl ? rr : rr - Tl)];
    float w = 0.025f / (float)(BB * Tl);  // (1-alpha)/(2*B*T)/10
    rowloss[NROWS + row] = w * (M + logf(S) - cross);
}

// ---------------------------------------------------------------------------
// Final flat sum of all weighted row losses -> out[0].
// ---------------------------------------------------------------------------
__global__ void reduce_kernel(const float* __restrict__ rowloss,
                              float* __restrict__ out) {
    __shared__ float sm[16];
    int tid = threadIdx.x;
    float s = 0.f;
    for (int i = tid; i < NROWS + NROWS_T; i += 1024) s += rowloss[i];
#pragma unroll
    for (int off = 32; off > 0; off >>= 1) s += __shfl_xor(s, off);
    if ((tid & 63) == 0) sm[tid >> 6] = s;
    __syncthreads();
    if (tid < 64) {
        float v = (tid < 16) ? sm[tid] : 0.f;
#pragma unroll
        for (int off = 8; off > 0; off >>= 1) v += __shfl_xor(v, off);
        if (tid == 0) out[0] = v;
    }
}

extern "C" void kernel_launch(void* const* d_in, const int* in_sizes, int n_in,
                              void* d_out, int out_size, void* d_ws,
                              size_t ws_size, hipStream_t stream) {
    const float* z1 = (const float*)d_in[0];
    const float* z2 = (const float*)d_in[1];
    const float* t  = (const float*)d_in[2];
    float* ws = (float*)d_ws;
    unsigned short* zb = (unsigned short*)ws;
    float* tpool = ws + FT;
    float2* part = (float2*)(ws + FPART);
    float* rowloss = ws + FROW;
    float* crossbuf = ws + FCROSS;  // total ws ~11.3 MB

    pool_lvl03<<<(NP1 + TTOT + 255) / 256, 256, 0, stream>>>(z1, z2, t, zb,
                                                             tpool);
    pool_lvl49<<<(NP2 + 255) / 256, 256, 0, stream>>>(zb);
    topk_inst_all<<<NROWS / 4, 256, 0, stream>>>(zb, t, tpool, rowloss);
    temporal_mfma<<<NTBLK, 256, 0, stream>>>(zb, part, crossbuf);
    merge_all<<<(NROWS_T + 255) / 256, 256, 0, stream>>>(part, crossbuf,
                                                         rowloss);
    reduce_kernel<<<1, 1024, 0, stream>>>(rowloss, (float*)d_out);
}